// Round 1
// baseline (1102.635 us; speedup 1.0000x reference)
//
#include <hip/hip_runtime.h>
#include <cmath>

#define IN_F 256
#define H_F  128
#define N_CLS 64

// ---------------- degree + norm ----------------
__global__ void deg_kernel(const int* __restrict__ src, const int* __restrict__ dst,
                           int* __restrict__ degs, int* __restrict__ degd, int E) {
  int i = blockIdx.x * blockDim.x + threadIdx.x;
  if (i < E) {
    atomicAdd(&degs[src[i]], 1);
    atomicAdd(&degd[dst[i]], 1);
  }
}

__global__ void norm_kernel(const int* __restrict__ degs, const int* __restrict__ degd,
                            float* __restrict__ ns, float* __restrict__ nd, int N) {
  int i = blockIdx.x * blockDim.x + threadIdx.x;
  if (i < N) {
    int a = degs[i], b = degd[i];
    ns[i] = a > 0 ? rsqrtf((float)a) : 0.f;
    nd[i] = b > 0 ? rsqrtf((float)b) : 0.f;
  }
}

// ---------------- CSR build: prefix scan + bucket fill ----------------
__global__ __launch_bounds__(1024) void scan_kernel(const int* __restrict__ deg,
                                                    int* __restrict__ off,
                                                    int* __restrict__ cursor, int N, int E) {
  __shared__ int part[1024];
  int t = threadIdx.x;
  int chunk = (N + 1023) >> 10;
  int lo = t * chunk;
  int hi = lo + chunk < N ? lo + chunk : N;
  int s = 0;
  for (int i = lo; i < hi; ++i) s += deg[i];
  part[t] = s;
  __syncthreads();
  for (int d = 1; d < 1024; d <<= 1) {
    int v = (t >= d) ? part[t - d] : 0;
    __syncthreads();
    part[t] += v;
    __syncthreads();
  }
  int run = (t == 0) ? 0 : part[t - 1];
  for (int i = lo; i < hi; ++i) { off[i] = run; cursor[i] = run; run += deg[i]; }
  if (t == 0) off[N] = E;
}

__global__ void fill_csr(const int* __restrict__ src, const int* __restrict__ dst,
                         int* __restrict__ cursor, int* __restrict__ csr, int E) {
  int i = blockIdx.x * blockDim.x + threadIdx.x;
  if (i < E) {
    int p = atomicAdd(&cursor[dst[i]], 1);
    csr[p] = src[i];
  }
}

// ---------------- tiled f32 GEMM with per-row output scale ----------------
// C[m, :] = (A[m, :] @ B) * scale[m]
template<int BM, int BN, int BK, int TM, int TN>
__global__ __launch_bounds__(256) void gemm_scale(const float* __restrict__ A,
                                                  const float* __restrict__ B,
                                                  const float* __restrict__ scale,
                                                  float* __restrict__ C,
                                                  int M, int K, int N) {
  __shared__ float As[BK][BM + 1];
  __shared__ float Bs[BK][BN + 1];
  const int TX = BN / TN;                 // threads along N
  int tid = threadIdx.x;
  int tx = tid % TX, ty = tid / TX;
  int m0 = blockIdx.x * BM;

  float acc[TM][TN];
#pragma unroll
  for (int i = 0; i < TM; ++i)
#pragma unroll
    for (int j = 0; j < TN; ++j) acc[i][j] = 0.f;

  for (int k0 = 0; k0 < K; k0 += BK) {
    for (int i = tid; i < BM * BK; i += 256) {
      int r = i / BK, c = i % BK;
      int gr = m0 + r;
      As[c][r] = (gr < M) ? A[(size_t)gr * K + k0 + c] : 0.f;
    }
    for (int i = tid; i < BK * BN; i += 256) {
      int r = i / BN, c = i % BN;
      Bs[r][c] = B[(size_t)(k0 + r) * N + c];
    }
    __syncthreads();
#pragma unroll
    for (int k = 0; k < BK; ++k) {
      float a[TM], b[TN];
#pragma unroll
      for (int i = 0; i < TM; ++i) a[i] = As[k][ty * TM + i];
#pragma unroll
      for (int j = 0; j < TN; ++j) b[j] = Bs[k][tx * TN + j];
#pragma unroll
      for (int i = 0; i < TM; ++i)
#pragma unroll
        for (int j = 0; j < TN; ++j) acc[i][j] += a[i] * b[j];
    }
    __syncthreads();
  }

  for (int i = 0; i < TM; ++i) {
    int gr = m0 + ty * TM + i;
    if (gr >= M) continue;
    float sc = scale[gr];
#pragma unroll
    for (int j = 0; j < TN; ++j)
      C[(size_t)gr * N + tx * TN + j] = acc[i][j] * sc;
  }
}

// ---------------- layer-1 gather: x2[n,:] = relu(nd[n]*sum_{e in in(n)} h1[src_e,:] + b1) ----------------
__global__ void gather1(const float* __restrict__ h1, const int* __restrict__ off,
                        const int* __restrict__ csr, const float* __restrict__ nd,
                        const float* __restrict__ b1, float* __restrict__ x2, int N) {
  int w = (blockIdx.x * blockDim.x + threadIdx.x) >> 6;
  int lane = threadIdx.x & 63;
  if (w >= N) return;
  int lo = off[w], hi = off[w + 1];
  const float2* h = (const float2*)h1;  // 128 floats = 64 float2 per row
  float sx = 0.f, sy = 0.f;
  for (int j = lo; j < hi; ++j) {
    int s = csr[j];
    float2 v = h[(size_t)s * 64 + lane];
    sx += v.x; sy += v.y;
  }
  float sc = nd[w];
  float2 bb = ((const float2*)b1)[lane];
  float2 o;
  o.x = fmaxf(sx * sc + bb.x, 0.f);
  o.y = fmaxf(sy * sc + bb.y, 0.f);
  ((float2*)x2)[(size_t)w * 64 + lane] = o;
}

// ---------------- layer-2 gather: out[n,:] = sigmoid(nd[n]*sum h2[src,:] + b2) ----------------
__global__ void gather2(const float* __restrict__ h2, const int* __restrict__ off,
                        const int* __restrict__ csr, const float* __restrict__ nd,
                        const float* __restrict__ b2, float* __restrict__ out, int N) {
  int w = (blockIdx.x * blockDim.x + threadIdx.x) >> 6;
  int lane = threadIdx.x & 63;
  if (w >= N) return;
  int lo = off[w], hi = off[w + 1];
  float s = 0.f;
  for (int j = lo; j < hi; ++j) {
    int sr = csr[j];
    s += h2[(size_t)sr * 64 + lane];
  }
  float v = s * nd[w] + b2[lane];
  out[(size_t)w * 64 + lane] = 1.f / (1.f + expf(-v));
}

extern "C" void kernel_launch(void* const* d_in, const int* in_sizes, int n_in,
                              void* d_out, int out_size, void* d_ws, size_t ws_size,
                              hipStream_t stream) {
  const float* feat = (const float*)d_in[0];
  const int*   src  = (const int*)d_in[1];
  const int*   dst  = (const int*)d_in[2];
  const float* W1   = (const float*)d_in[3];
  const float* b1   = (const float*)d_in[4];
  const float* W2   = (const float*)d_in[5];
  const float* b2   = (const float*)d_in[6];
  float* out = (float*)d_out;

  const int N = in_sizes[0] / IN_F;   // 100000
  const int E = in_sizes[1];          // 1600000

  // workspace layout (256B-aligned slices)
  size_t off = 0;
  auto alloc = [&](size_t bytes) -> void* {
    void* p = (char*)d_ws + off;
    off = (off + bytes + 255) & ~(size_t)255;
    return p;
  };
  int*   deg_s   = (int*)alloc((size_t)N * 4);
  int*   deg_d   = (int*)alloc((size_t)N * 4);
  float* norm_s  = (float*)alloc((size_t)N * 4);
  float* norm_d  = (float*)alloc((size_t)N * 4);
  int*   row_off = (int*)alloc((size_t)(N + 1) * 4);
  int*   cursor  = (int*)alloc((size_t)N * 4);
  int*   csr     = (int*)alloc((size_t)E * 4);
  float* h1      = (float*)alloc((size_t)N * H_F * 4);   // (feat@W1)*norm_src
  float* x2      = (float*)alloc((size_t)N * H_F * 4);   // relu layer-1 output
  float* h2      = (float*)alloc((size_t)N * N_CLS * 4); // (x2@W2)*norm_src
  (void)ws_size;

  hipMemsetAsync(deg_s, 0, (size_t)N * 4, stream);
  hipMemsetAsync(deg_d, 0, (size_t)N * 4, stream);

  deg_kernel<<<(E + 255) / 256, 256, 0, stream>>>(src, dst, deg_s, deg_d, E);
  norm_kernel<<<(N + 255) / 256, 256, 0, stream>>>(deg_s, deg_d, norm_s, norm_d, N);
  scan_kernel<<<1, 1024, 0, stream>>>(deg_d, row_off, cursor, N, E);
  fill_csr<<<(E + 255) / 256, 256, 0, stream>>>(src, dst, cursor, csr, E);

  // layer 1: h1 = (feat @ W1) * norm_src
  gemm_scale<64, 128, 16, 4, 8><<<(N + 63) / 64, 256, 0, stream>>>(
      feat, W1, norm_s, h1, N, IN_F, H_F);
  // x2 = relu(norm_dst * segsum(h1[src]) + b1)
  gather1<<<(N * 64 + 255) / 256, 256, 0, stream>>>(h1, row_off, csr, norm_d, b1, x2, N);

  // layer 2: h2 = (x2 @ W2) * norm_src
  gemm_scale<64, 64, 16, 4, 4><<<(N + 63) / 64, 256, 0, stream>>>(
      x2, W2, norm_s, h2, N, H_F, N_CLS);
  // out = sigmoid(norm_dst * segsum(h2[src]) + b2)
  gather2<<<(N * 64 + 255) / 256, 256, 0, stream>>>(h2, row_off, csr, norm_d, b2, out, N);
}

// Round 2
// 852.528 us; speedup vs baseline: 1.2934x; 1.2934x over previous
//
#include <hip/hip_runtime.h>
#include <cmath>

#define IN_F 256
#define H_F  128
#define N_CLS 64

typedef __attribute__((ext_vector_type(8))) short bf16x8;
typedef __attribute__((ext_vector_type(4))) float f32x4;

__device__ __forceinline__ ushort f2bf(float x) {
  unsigned b = __builtin_bit_cast(unsigned, x);
  b += 0x7FFF + ((b >> 16) & 1);          // RNE
  return (ushort)(b >> 16);
}

// ---------------- bf16 conversion kernels ----------------
__global__ void conv_feat(const float* __restrict__ in, ushort* __restrict__ out, int n4) {
  int i = blockIdx.x * blockDim.x + threadIdx.x;
  int stride = gridDim.x * blockDim.x;
  for (; i < n4; i += stride) {
    float4 v = ((const float4*)in)[i];
    ushort4 o;
    o.x = f2bf(v.x); o.y = f2bf(v.y); o.z = f2bf(v.z); o.w = f2bf(v.w);
    ((ushort4*)out)[i] = o;
  }
}

// WT[n][k] = bf16(W[k][n])  (tiny)
__global__ void conv_wT(const float* __restrict__ W, ushort* __restrict__ WT, int K, int N) {
  int i = blockIdx.x * blockDim.x + threadIdx.x;
  if (i >= K * N) return;
  int k = i / N, n = i % N;
  WT[n * K + k] = f2bf(W[i]);
}

// ---------------- degree + norm ----------------
__global__ void deg_kernel(const int* __restrict__ src, const int* __restrict__ dst,
                           int* __restrict__ degs, int* __restrict__ degd, int E) {
  int i = blockIdx.x * blockDim.x + threadIdx.x;
  if (i < E) {
    atomicAdd(&degs[src[i]], 1);
    atomicAdd(&degd[dst[i]], 1);
  }
}

__global__ void norm_kernel(const int* __restrict__ degs, const int* __restrict__ degd,
                            float* __restrict__ ns, float* __restrict__ nd, int N) {
  int i = blockIdx.x * blockDim.x + threadIdx.x;
  if (i < N) {
    int a = degs[i], b = degd[i];
    ns[i] = a > 0 ? rsqrtf((float)a) : 0.f;
    nd[i] = b > 0 ? rsqrtf((float)b) : 0.f;
  }
}

// ---------------- CSR build ----------------
__global__ __launch_bounds__(1024) void scan_kernel(const int* __restrict__ deg,
                                                    int* __restrict__ off,
                                                    int* __restrict__ cursor, int N, int E) {
  __shared__ int part[1024];
  int t = threadIdx.x;
  int chunk = (N + 1023) >> 10;
  int lo = t * chunk;
  int hi = lo + chunk < N ? lo + chunk : N;
  int s = 0;
  for (int i = lo; i < hi; ++i) s += deg[i];
  part[t] = s;
  __syncthreads();
  for (int d = 1; d < 1024; d <<= 1) {
    int v = (t >= d) ? part[t - d] : 0;
    __syncthreads();
    part[t] += v;
    __syncthreads();
  }
  int run = (t == 0) ? 0 : part[t - 1];
  for (int i = lo; i < hi; ++i) { off[i] = run; cursor[i] = run; run += deg[i]; }
  if (t == 0) off[N] = E;
}

__global__ void fill_csr(const int* __restrict__ src, const int* __restrict__ dst,
                         int* __restrict__ cursor, int* __restrict__ csr, int E) {
  int i = blockIdx.x * blockDim.x + threadIdx.x;
  if (i < E) {
    int p = atomicAdd(&cursor[dst[i]], 1);
    csr[p] = src[i];
  }
}

// ---------------- bf16 MFMA GEMM with per-row output scale ----------------
// C[m, 0:BN] = (A[m, 0:KTOT] @ B) * scale[m]; BT is B transposed [BN][KTOT] bf16.
// BK=64; LDS rows are 128B wide; XOR swizzle byte^=((row&7)<<4) applied on the
// pre-swizzled GLOBAL source (global_load_lds writes linearly) and on ds_read.
template<int BM, int BN, int KTOT, int WM, int WN>
__global__ __launch_bounds__(256) void mfma_gemm_scale(
    const ushort* __restrict__ A, const ushort* __restrict__ BT,
    const float* __restrict__ scale, float* __restrict__ C, int M) {
  constexpr int BK = 64;
  constexpr int FM = (BM / WM) / 16;
  constexpr int FN = (BN / WN) / 16;
  constexpr int ABYTES = BM * BK * 2;
  constexpr int BBYTES = BN * BK * 2;
  __shared__ char lds[ABYTES + BBYTES];
  char* Asm = lds;
  char* Bsm = lds + ABYTES;

  const int tid = threadIdx.x;
  const int lane = tid & 63;
  const int w = tid >> 6;
  const int wm = w / WN, wn = w % WN;
  const int m0 = blockIdx.x * BM;

  f32x4 acc[FM][FN];
#pragma unroll
  for (int m = 0; m < FM; ++m)
#pragma unroll
    for (int n = 0; n < FN; ++n) acc[m][n] = (f32x4){0.f, 0.f, 0.f, 0.f};

  const int ra = lane & 15;   // A-row / B-col within 16
  const int kg = lane >> 4;   // k-group (8 bf16 = 16B each)

  for (int kt = 0; kt < KTOT / BK; ++kt) {
    // ---- stage A tile [BM][BK] (pre-swizzled source, linear LDS dest) ----
#pragma unroll
    for (int s = 0; s < ABYTES / 4096; ++s) {
      int L = s * 4096 + tid * 16;
      int r = L >> 7;
      int slot = (L >> 4) & 7;
      int gr = m0 + r; if (gr >= M) gr = M - 1;
      const char* gp = (const char*)A + (size_t)gr * (KTOT * 2) + kt * (BK * 2)
                     + ((slot * 16) ^ ((r & 7) << 4));
      __builtin_amdgcn_global_load_lds(
          (const __attribute__((address_space(1))) unsigned*)gp,
          (__attribute__((address_space(3))) unsigned*)(Asm + L), 16, 0, 0);
    }
    // ---- stage B tile [BN][BK] ----
#pragma unroll
    for (int s = 0; s < BBYTES / 4096; ++s) {
      int L = s * 4096 + tid * 16;
      int r = L >> 7;
      int slot = (L >> 4) & 7;
      const char* gp = (const char*)BT + (size_t)r * (KTOT * 2) + kt * (BK * 2)
                     + ((slot * 16) ^ ((r & 7) << 4));
      __builtin_amdgcn_global_load_lds(
          (const __attribute__((address_space(1))) unsigned*)gp,
          (__attribute__((address_space(3))) unsigned*)(Bsm + L), 16, 0, 0);
    }
    __syncthreads();   // drains vmcnt + lgkmcnt

    // ---- compute: 2 k-substeps of 32 ----
#pragma unroll
    for (int ks = 0; ks < 2; ++ks) {
      bf16x8 af[FM], bfr[FN];
#pragma unroll
      for (int m = 0; m < FM; ++m) {
        int r = wm * (BM / WM) + m * 16 + ra;
        int cb = ks * 64 + kg * 16;
        af[m] = *(const bf16x8*)(Asm + r * 128 + (cb ^ ((r & 7) << 4)));
      }
#pragma unroll
      for (int n = 0; n < FN; ++n) {
        int c = wn * (BN / WN) + n * 16 + ra;
        int cb = ks * 64 + kg * 16;
        bfr[n] = *(const bf16x8*)(Bsm + c * 128 + (cb ^ ((c & 7) << 4)));
      }
#pragma unroll
      for (int m = 0; m < FM; ++m)
#pragma unroll
        for (int n = 0; n < FN; ++n)
          acc[m][n] = __builtin_amdgcn_mfma_f32_16x16x32_bf16(af[m], bfr[n], acc[m][n], 0, 0, 0);
    }
    __syncthreads();
  }

  // ---- epilogue: scale by norm_src, write f32 ----
#pragma unroll
  for (int m = 0; m < FM; ++m) {
#pragma unroll
    for (int j = 0; j < 4; ++j) {
      int rl = wm * (BM / WM) + m * 16 + (lane >> 4) * 4 + j;
      int gr = m0 + rl;
      if (gr < M) {
        float sc = scale[gr];
#pragma unroll
        for (int n = 0; n < FN; ++n) {
          int c = wn * (BN / WN) + n * 16 + (lane & 15);
          C[(size_t)gr * BN + c] = acc[m][n][j] * sc;
        }
      }
    }
  }
}

// ---------------- gathers ----------------
// x2[n,:] = bf16(relu(nd[n]*sum_{e in in(n)} h1[src_e,:] + b1))
__global__ void gather1(const float* __restrict__ h1, const int* __restrict__ off,
                        const int* __restrict__ csr, const float* __restrict__ nd,
                        const float* __restrict__ b1, ushort* __restrict__ x2, int N) {
  int w = (blockIdx.x * blockDim.x + threadIdx.x) >> 6;
  int lane = threadIdx.x & 63;
  if (w >= N) return;
  int lo = off[w], hi = off[w + 1];
  const float2* h = (const float2*)h1;
  float sx = 0.f, sy = 0.f;
  for (int j = lo; j < hi; ++j) {
    int s = csr[j];
    float2 v = h[(size_t)s * 64 + lane];
    sx += v.x; sy += v.y;
  }
  float sc = nd[w];
  float2 bb = ((const float2*)b1)[lane];
  float ox = fmaxf(sx * sc + bb.x, 0.f);
  float oy = fmaxf(sy * sc + bb.y, 0.f);
  ushort2 o; o.x = f2bf(ox); o.y = f2bf(oy);
  ((ushort2*)x2)[(size_t)w * 64 + lane] = o;
}

// out[n,:] = sigmoid(nd[n]*sum h2[src,:] + b2)
__global__ void gather2(const float* __restrict__ h2, const int* __restrict__ off,
                        const int* __restrict__ csr, const float* __restrict__ nd,
                        const float* __restrict__ b2, float* __restrict__ out, int N) {
  int w = (blockIdx.x * blockDim.x + threadIdx.x) >> 6;
  int lane = threadIdx.x & 63;
  if (w >= N) return;
  int lo = off[w], hi = off[w + 1];
  float s = 0.f;
  for (int j = lo; j < hi; ++j) {
    int sr = csr[j];
    s += h2[(size_t)sr * 64 + lane];
  }
  float v = s * nd[w] + b2[lane];
  out[(size_t)w * 64 + lane] = 1.f / (1.f + expf(-v));
}

extern "C" void kernel_launch(void* const* d_in, const int* in_sizes, int n_in,
                              void* d_out, int out_size, void* d_ws, size_t ws_size,
                              hipStream_t stream) {
  const float* feat = (const float*)d_in[0];
  const int*   src  = (const int*)d_in[1];
  const int*   dst  = (const int*)d_in[2];
  const float* W1   = (const float*)d_in[3];
  const float* b1   = (const float*)d_in[4];
  const float* W2   = (const float*)d_in[5];
  const float* b2   = (const float*)d_in[6];
  float* out = (float*)d_out;

  const int N = in_sizes[0] / IN_F;   // 100000
  const int E = in_sizes[1];          // 1600000

  size_t off = 0;
  auto alloc = [&](size_t bytes) -> void* {
    void* p = (char*)d_ws + off;
    off = (off + bytes + 255) & ~(size_t)255;
    return p;
  };
  int*    deg_s   = (int*)alloc((size_t)N * 4);
  int*    deg_d   = (int*)alloc((size_t)N * 4);
  float*  norm_s  = (float*)alloc((size_t)N * 4);
  float*  norm_d  = (float*)alloc((size_t)N * 4);
  int*    row_off = (int*)alloc((size_t)(N + 1) * 4);
  int*    cursor  = (int*)alloc((size_t)N * 4);
  int*    csr     = (int*)alloc((size_t)E * 4);
  ushort* featbf  = (ushort*)alloc((size_t)N * IN_F * 2);
  ushort* w1t     = (ushort*)alloc((size_t)H_F * IN_F * 2);
  ushort* w2t     = (ushort*)alloc((size_t)N_CLS * H_F * 2);
  float*  h1      = (float*)alloc((size_t)N * H_F * 4);
  ushort* x2bf    = (ushort*)alloc((size_t)N * H_F * 2);
  float*  h2      = (float*)alloc((size_t)N * N_CLS * 4);
  (void)ws_size;

  hipMemsetAsync(deg_s, 0, (size_t)N * 4, stream);
  hipMemsetAsync(deg_d, 0, (size_t)N * 4, stream);

  conv_feat<<<2048, 256, 0, stream>>>(feat, featbf, N * IN_F / 4);
  conv_wT<<<(IN_F * H_F + 255) / 256, 256, 0, stream>>>(W1, w1t, IN_F, H_F);
  conv_wT<<<(H_F * N_CLS + 255) / 256, 256, 0, stream>>>(W2, w2t, H_F, N_CLS);

  deg_kernel<<<(E + 255) / 256, 256, 0, stream>>>(src, dst, deg_s, deg_d, E);
  norm_kernel<<<(N + 255) / 256, 256, 0, stream>>>(deg_s, deg_d, norm_s, norm_d, N);
  scan_kernel<<<1, 1024, 0, stream>>>(deg_d, row_off, cursor, N, E);
  fill_csr<<<(E + 255) / 256, 256, 0, stream>>>(src, dst, cursor, csr, E);

  // layer 1: h1 = (feat @ W1) * norm_src   [bf16 MFMA]
  mfma_gemm_scale<128, 128, 256, 2, 2><<<(N + 127) / 128, 256, 0, stream>>>(
      featbf, w1t, norm_s, h1, N);
  gather1<<<(N * 64 + 255) / 256, 256, 0, stream>>>(h1, row_off, csr, norm_d, b1, x2bf, N);

  // layer 2: h2 = (x2 @ W2) * norm_src   [bf16 MFMA]
  mfma_gemm_scale<128, 64, 128, 2, 2><<<(N + 127) / 128, 256, 0, stream>>>(
      x2bf, w2t, norm_s, h2, N);
  gather2<<<(N * 64 + 255) / 256, 256, 0, stream>>>(h2, row_off, csr, norm_d, b2, out, N);
}

// Round 3
// 640.006 us; speedup vs baseline: 1.7229x; 1.3321x over previous
//
#include <hip/hip_runtime.h>
#include <cmath>

#define IN_F 256
#define H_F  128
#define N_CLS 64
#define SCAN_CHUNK 2048   // 256 threads * 8 elems

typedef __attribute__((ext_vector_type(8))) short bf16x8;
typedef __attribute__((ext_vector_type(4))) float f32x4;

__device__ __forceinline__ ushort f2bf(float x) {
  unsigned b = __builtin_bit_cast(unsigned, x);
  b += 0x7FFF + ((b >> 16) & 1);          // RNE
  return (ushort)(b >> 16);
}

// ---------------- bf16 conversion kernels ----------------
__global__ void conv_feat(const float* __restrict__ in, ushort* __restrict__ out, int n4) {
  int i = blockIdx.x * blockDim.x + threadIdx.x;
  int stride = gridDim.x * blockDim.x;
  for (; i < n4; i += stride) {
    float4 v = ((const float4*)in)[i];
    ushort4 o;
    o.x = f2bf(v.x); o.y = f2bf(v.y); o.z = f2bf(v.z); o.w = f2bf(v.w);
    ((ushort4*)out)[i] = o;
  }
}

// WT[n][k] = bf16(W[k][n])  (tiny)
__global__ void conv_wT(const float* __restrict__ W, ushort* __restrict__ WT, int K, int N) {
  int i = blockIdx.x * blockDim.x + threadIdx.x;
  if (i >= K * N) return;
  int k = i / N, n = i % N;
  WT[n * K + k] = f2bf(W[i]);
}

// ---------------- degree + norm ----------------
__global__ void deg_kernel(const int* __restrict__ src, const int* __restrict__ dst,
                           int* __restrict__ degs, int* __restrict__ degd, int E) {
  int i = blockIdx.x * blockDim.x + threadIdx.x;
  if (i < E) {
    atomicAdd(&degs[src[i]], 1);
    atomicAdd(&degd[dst[i]], 1);
  }
}

__global__ void norm_kernel(const int* __restrict__ degs, const int* __restrict__ degd,
                            float* __restrict__ ns, float* __restrict__ nd, int N) {
  int i = blockIdx.x * blockDim.x + threadIdx.x;
  if (i < N) {
    int a = degs[i], b = degd[i];
    ns[i] = a > 0 ? rsqrtf((float)a) : 0.f;
    nd[i] = b > 0 ? rsqrtf((float)b) : 0.f;
  }
}

// ---------------- CSR build: 3-kernel decoupled scan ----------------
__global__ void scan_part(const int* __restrict__ deg, int* __restrict__ bsum, int N) {
  int base = blockIdx.x * SCAN_CHUNK + threadIdx.x * 8;
  int s = 0;
#pragma unroll
  for (int j = 0; j < 8; ++j) {
    int i = base + j;
    if (i < N) s += deg[i];
  }
#pragma unroll
  for (int d = 1; d < 64; d <<= 1) s += __shfl_xor(s, d);
  __shared__ int ws[4];
  int lane = threadIdx.x & 63, w = threadIdx.x >> 6;
  if (lane == 0) ws[w] = s;
  __syncthreads();
  if (threadIdx.x == 0) bsum[blockIdx.x] = ws[0] + ws[1] + ws[2] + ws[3];
}

__global__ __launch_bounds__(1024) void scan_bsum(int* __restrict__ bsum, int nb) {
  __shared__ int sm[1024];
  int t = threadIdx.x;
  sm[t] = (t < nb) ? bsum[t] : 0;
  __syncthreads();
  for (int d = 1; d < 1024; d <<= 1) {
    int v = (t >= d) ? sm[t - d] : 0;
    __syncthreads();
    sm[t] += v;
    __syncthreads();
  }
  if (t < nb) bsum[t] = (t == 0) ? 0 : sm[t - 1];   // exclusive
}

__global__ void scan_final(const int* __restrict__ deg, const int* __restrict__ bsum_ex,
                           int* __restrict__ off, int* __restrict__ cursor, int N, int E) {
  int base = blockIdx.x * SCAN_CHUNK + threadIdx.x * 8;
  int v[8], pre[8];
  int s = 0;
#pragma unroll
  for (int j = 0; j < 8; ++j) {
    int i = base + j;
    v[j] = (i < N) ? deg[i] : 0;
    pre[j] = s;
    s += v[j];
  }
  int lane = threadIdx.x & 63, w = threadIdx.x >> 6;
  int inc = s;
#pragma unroll
  for (int d = 1; d < 64; d <<= 1) {
    int u = __shfl_up(inc, d);
    if (lane >= d) inc += u;
  }
  __shared__ int wsum[4], woff[4];
  if (lane == 63) wsum[w] = inc;
  __syncthreads();
  if (threadIdx.x == 0) {
    int r = 0;
    for (int q = 0; q < 4; ++q) { woff[q] = r; r += wsum[q]; }
  }
  __syncthreads();
  int ex = (inc - s) + woff[w] + bsum_ex[blockIdx.x];
#pragma unroll
  for (int j = 0; j < 8; ++j) {
    int i = base + j;
    if (i < N) {
      int o = ex + pre[j];
      off[i] = o;
      cursor[i] = o;
    }
  }
  if (blockIdx.x == 0 && threadIdx.x == 0) off[N] = E;
}

__global__ void fill_csr(const int* __restrict__ src, const int* __restrict__ dst,
                         int* __restrict__ cursor, int* __restrict__ csr, int E) {
  int i = blockIdx.x * blockDim.x + threadIdx.x;
  if (i < E) {
    int p = atomicAdd(&cursor[dst[i]], 1);
    csr[p] = src[i];
  }
}

// ---------------- bf16 MFMA GEMM with per-row output scale ----------------
// C[m, 0:BN] = (A[m, 0:KTOT] @ B) * scale[m]; BT is B transposed [BN][KTOT] bf16.
// BK=64; LDS rows are 128B wide; XOR swizzle byte^=((row&7)<<4) applied on the
// pre-swizzled GLOBAL source (global_load_lds writes linearly) and on ds_read.
template<int BM, int BN, int KTOT, int WM, int WN>
__global__ __launch_bounds__(256) void mfma_gemm_scale(
    const ushort* __restrict__ A, const ushort* __restrict__ BT,
    const float* __restrict__ scale, float* __restrict__ C, int M) {
  constexpr int BK = 64;
  constexpr int FM = (BM / WM) / 16;
  constexpr int FN = (BN / WN) / 16;
  constexpr int ABYTES = BM * BK * 2;
  constexpr int BBYTES = BN * BK * 2;
  __shared__ char lds[ABYTES + BBYTES];
  char* Asm = lds;
  char* Bsm = lds + ABYTES;

  const int tid = threadIdx.x;
  const int lane = tid & 63;
  const int w = tid >> 6;
  const int wm = w / WN, wn = w % WN;
  const int m0 = blockIdx.x * BM;

  f32x4 acc[FM][FN];
#pragma unroll
  for (int m = 0; m < FM; ++m)
#pragma unroll
    for (int n = 0; n < FN; ++n) acc[m][n] = (f32x4){0.f, 0.f, 0.f, 0.f};

  const int ra = lane & 15;   // A-row / B-col within 16
  const int kg = lane >> 4;   // k-group (8 bf16 = 16B each)

  for (int kt = 0; kt < KTOT / BK; ++kt) {
    // ---- stage A tile [BM][BK] (pre-swizzled source, linear LDS dest) ----
#pragma unroll
    for (int s = 0; s < ABYTES / 4096; ++s) {
      int L = s * 4096 + tid * 16;
      int r = L >> 7;
      int slot = (L >> 4) & 7;
      int gr = m0 + r; if (gr >= M) gr = M - 1;
      const char* gp = (const char*)A + (size_t)gr * (KTOT * 2) + kt * (BK * 2)
                     + ((slot * 16) ^ ((r & 7) << 4));
      __builtin_amdgcn_global_load_lds(
          (const __attribute__((address_space(1))) unsigned*)gp,
          (__attribute__((address_space(3))) unsigned*)(Asm + L), 16, 0, 0);
    }
    // ---- stage B tile [BN][BK] ----
#pragma unroll
    for (int s = 0; s < BBYTES / 4096; ++s) {
      int L = s * 4096 + tid * 16;
      int r = L >> 7;
      int slot = (L >> 4) & 7;
      const char* gp = (const char*)BT + (size_t)r * (KTOT * 2) + kt * (BK * 2)
                     + ((slot * 16) ^ ((r & 7) << 4));
      __builtin_amdgcn_global_load_lds(
          (const __attribute__((address_space(1))) unsigned*)gp,
          (__attribute__((address_space(3))) unsigned*)(Bsm + L), 16, 0, 0);
    }
    __syncthreads();   // drains vmcnt + lgkmcnt

    // ---- compute: 2 k-substeps of 32 ----
#pragma unroll
    for (int ks = 0; ks < 2; ++ks) {
      bf16x8 af[FM], bfr[FN];
#pragma unroll
      for (int m = 0; m < FM; ++m) {
        int r = wm * (BM / WM) + m * 16 + ra;
        int cb = ks * 64 + kg * 16;
        af[m] = *(const bf16x8*)(Asm + r * 128 + (cb ^ ((r & 7) << 4)));
      }
#pragma unroll
      for (int n = 0; n < FN; ++n) {
        int c = wn * (BN / WN) + n * 16 + ra;
        int cb = ks * 64 + kg * 16;
        bfr[n] = *(const bf16x8*)(Bsm + c * 128 + (cb ^ ((c & 7) << 4)));
      }
#pragma unroll
      for (int m = 0; m < FM; ++m)
#pragma unroll
        for (int n = 0; n < FN; ++n)
          acc[m][n] = __builtin_amdgcn_mfma_f32_16x16x32_bf16(af[m], bfr[n], acc[m][n], 0, 0, 0);
    }
    __syncthreads();
  }

  // ---- epilogue: scale by norm_src, write f32 ----
#pragma unroll
  for (int m = 0; m < FM; ++m) {
#pragma unroll
    for (int j = 0; j < 4; ++j) {
      int rl = wm * (BM / WM) + m * 16 + (lane >> 4) * 4 + j;
      int gr = m0 + rl;
      if (gr < M) {
        float sc = scale[gr];
#pragma unroll
        for (int n = 0; n < FN; ++n) {
          int c = wn * (BN / WN) + n * 16 + (lane & 15);
          C[(size_t)gr * BN + c] = acc[m][n][j] * sc;
        }
      }
    }
  }
}

// ---------------- gathers ----------------
// x2[n,:] = bf16(relu(nd[n]*sum_{e in in(n)} h1[src_e,:] + b1))
__global__ void gather1(const float* __restrict__ h1, const int* __restrict__ off,
                        const int* __restrict__ csr, const float* __restrict__ nd,
                        const float* __restrict__ b1, ushort* __restrict__ x2, int N) {
  int w = (blockIdx.x * blockDim.x + threadIdx.x) >> 6;
  int lane = threadIdx.x & 63;
  if (w >= N) return;
  int lo = off[w], hi = off[w + 1];
  const float2* h = (const float2*)h1;
  float sx = 0.f, sy = 0.f;
  for (int j = lo; j < hi; ++j) {
    int s = csr[j];
    float2 v = h[(size_t)s * 64 + lane];
    sx += v.x; sy += v.y;
  }
  float sc = nd[w];
  float2 bb = ((const float2*)b1)[lane];
  float ox = fmaxf(sx * sc + bb.x, 0.f);
  float oy = fmaxf(sy * sc + bb.y, 0.f);
  ushort2 o; o.x = f2bf(ox); o.y = f2bf(oy);
  ((ushort2*)x2)[(size_t)w * 64 + lane] = o;
}

// out[n,:] = sigmoid(nd[n]*sum h2[src,:] + b2)
__global__ void gather2(const float* __restrict__ h2, const int* __restrict__ off,
                        const int* __restrict__ csr, const float* __restrict__ nd,
                        const float* __restrict__ b2, float* __restrict__ out, int N) {
  int w = (blockIdx.x * blockDim.x + threadIdx.x) >> 6;
  int lane = threadIdx.x & 63;
  if (w >= N) return;
  int lo = off[w], hi = off[w + 1];
  float s = 0.f;
  for (int j = lo; j < hi; ++j) {
    int sr = csr[j];
    s += h2[(size_t)sr * 64 + lane];
  }
  float v = s * nd[w] + b2[lane];
  out[(size_t)w * 64 + lane] = 1.f / (1.f + expf(-v));
}

extern "C" void kernel_launch(void* const* d_in, const int* in_sizes, int n_in,
                              void* d_out, int out_size, void* d_ws, size_t ws_size,
                              hipStream_t stream) {
  const float* feat = (const float*)d_in[0];
  const int*   src  = (const int*)d_in[1];
  const int*   dst  = (const int*)d_in[2];
  const float* W1   = (const float*)d_in[3];
  const float* b1   = (const float*)d_in[4];
  const float* W2   = (const float*)d_in[5];
  const float* b2   = (const float*)d_in[6];
  float* out = (float*)d_out;

  const int N = in_sizes[0] / IN_F;   // 100000
  const int E = in_sizes[1];          // 1600000

  size_t off = 0;
  auto alloc = [&](size_t bytes) -> void* {
    void* p = (char*)d_ws + off;
    off = (off + bytes + 255) & ~(size_t)255;
    return p;
  };
  int*    deg_s   = (int*)alloc((size_t)N * 4);
  int*    deg_d   = (int*)alloc((size_t)N * 4);
  float*  norm_s  = (float*)alloc((size_t)N * 4);
  float*  norm_d  = (float*)alloc((size_t)N * 4);
  int*    row_off = (int*)alloc((size_t)(N + 1) * 4);
  int*    cursor  = (int*)alloc((size_t)N * 4);
  int*    bsum    = (int*)alloc((size_t)1024 * 4);
  int*    csr     = (int*)alloc((size_t)E * 4);
  ushort* featbf  = (ushort*)alloc((size_t)N * IN_F * 2);
  ushort* w1t     = (ushort*)alloc((size_t)H_F * IN_F * 2);
  ushort* w2t     = (ushort*)alloc((size_t)N_CLS * H_F * 2);
  float*  h1      = (float*)alloc((size_t)N * H_F * 4);
  ushort* x2bf    = (ushort*)alloc((size_t)N * H_F * 2);
  float*  h2      = (float*)alloc((size_t)N * N_CLS * 4);
  (void)ws_size;

  hipMemsetAsync(deg_s, 0, (size_t)N * 4, stream);
  hipMemsetAsync(deg_d, 0, (size_t)N * 4, stream);

  conv_feat<<<2048, 256, 0, stream>>>(feat, featbf, N * IN_F / 4);
  conv_wT<<<(IN_F * H_F + 255) / 256, 256, 0, stream>>>(W1, w1t, IN_F, H_F);
  conv_wT<<<(H_F * N_CLS + 255) / 256, 256, 0, stream>>>(W2, w2t, H_F, N_CLS);

  deg_kernel<<<(E + 255) / 256, 256, 0, stream>>>(src, dst, deg_s, deg_d, E);
  norm_kernel<<<(N + 255) / 256, 256, 0, stream>>>(deg_s, deg_d, norm_s, norm_d, N);

  const int NB = (N + SCAN_CHUNK - 1) / SCAN_CHUNK;   // 49
  scan_part<<<NB, 256, 0, stream>>>(deg_d, bsum, N);
  scan_bsum<<<1, 1024, 0, stream>>>(bsum, NB);
  scan_final<<<NB, 256, 0, stream>>>(deg_d, bsum, row_off, cursor, N, E);
  fill_csr<<<(E + 255) / 256, 256, 0, stream>>>(src, dst, cursor, csr, E);

  // layer 1: h1 = (feat @ W1) * norm_src   [bf16 MFMA]
  mfma_gemm_scale<128, 128, 256, 2, 2><<<(N + 127) / 128, 256, 0, stream>>>(
      featbf, w1t, norm_s, h1, N);
  gather1<<<(N * 64 + 255) / 256, 256, 0, stream>>>(h1, row_off, csr, norm_d, b1, x2bf, N);

  // layer 2: h2 = (x2 @ W2) * norm_src   [bf16 MFMA]
  mfma_gemm_scale<128, 64, 128, 2, 2><<<(N + 127) / 128, 256, 0, stream>>>(
      x2bf, w2t, norm_s, h2, N);
  gather2<<<(N * 64 + 255) / 256, 256, 0, stream>>>(h2, row_off, csr, norm_d, b2, out, N);
}

// Round 4
// 619.620 us; speedup vs baseline: 1.7795x; 1.0329x over previous
//
#include <hip/hip_runtime.h>
#include <cmath>

#define IN_F 256
#define H_F  128
#define N_CLS 64
#define SCAN_CHUNK 2048   // 256 threads * 8 elems

typedef __attribute__((ext_vector_type(8))) short bf16x8;
typedef __attribute__((ext_vector_type(4))) float f32x4;

__device__ __forceinline__ ushort f2bf(float x) {
  unsigned b = __builtin_bit_cast(unsigned, x);
  b += 0x7FFF + ((b >> 16) & 1);          // RNE
  return (ushort)(b >> 16);
}
__device__ __forceinline__ float bf2f(ushort u) {
  unsigned b = ((unsigned)u) << 16;
  return __builtin_bit_cast(float, b);
}

// ---------------- bf16 conversion kernels ----------------
__global__ void conv_feat(const float* __restrict__ in, ushort* __restrict__ out, int n4) {
  int i = blockIdx.x * blockDim.x + threadIdx.x;
  int stride = gridDim.x * blockDim.x;
  for (; i < n4; i += stride) {
    float4 v = ((const float4*)in)[i];
    ushort4 o;
    o.x = f2bf(v.x); o.y = f2bf(v.y); o.z = f2bf(v.z); o.w = f2bf(v.w);
    ((ushort4*)out)[i] = o;
  }
}

// WT[n][k] = bf16(W[k][n])  (tiny)
__global__ void conv_wT(const float* __restrict__ W, ushort* __restrict__ WT, int K, int N) {
  int i = blockIdx.x * blockDim.x + threadIdx.x;
  if (i >= K * N) return;
  int k = i / N, n = i % N;
  WT[n * K + k] = f2bf(W[i]);
}

// ---------------- degree + norm ----------------
__global__ void deg_kernel(const int* __restrict__ src, const int* __restrict__ dst,
                           int* __restrict__ degs, int* __restrict__ degd, int E) {
  int i = blockIdx.x * blockDim.x + threadIdx.x;
  if (i < E) {
    atomicAdd(&degs[src[i]], 1);
    atomicAdd(&degd[dst[i]], 1);
  }
}

__global__ void norm_kernel(const int* __restrict__ degs, const int* __restrict__ degd,
                            float* __restrict__ ns, float* __restrict__ nd, int N) {
  int i = blockIdx.x * blockDim.x + threadIdx.x;
  if (i < N) {
    int a = degs[i], b = degd[i];
    ns[i] = a > 0 ? rsqrtf((float)a) : 0.f;
    nd[i] = b > 0 ? rsqrtf((float)b) : 0.f;
  }
}

// ---------------- CSR build: 3-kernel decoupled scan ----------------
__global__ void scan_part(const int* __restrict__ deg, int* __restrict__ bsum, int N) {
  int base = blockIdx.x * SCAN_CHUNK + threadIdx.x * 8;
  int s = 0;
#pragma unroll
  for (int j = 0; j < 8; ++j) {
    int i = base + j;
    if (i < N) s += deg[i];
  }
#pragma unroll
  for (int d = 1; d < 64; d <<= 1) s += __shfl_xor(s, d);
  __shared__ int ws[4];
  int lane = threadIdx.x & 63, w = threadIdx.x >> 6;
  if (lane == 0) ws[w] = s;
  __syncthreads();
  if (threadIdx.x == 0) bsum[blockIdx.x] = ws[0] + ws[1] + ws[2] + ws[3];
}

__global__ __launch_bounds__(1024) void scan_bsum(int* __restrict__ bsum, int nb) {
  __shared__ int sm[1024];
  int t = threadIdx.x;
  sm[t] = (t < nb) ? bsum[t] : 0;
  __syncthreads();
  for (int d = 1; d < 1024; d <<= 1) {
    int v = (t >= d) ? sm[t - d] : 0;
    __syncthreads();
    sm[t] += v;
    __syncthreads();
  }
  if (t < nb) bsum[t] = (t == 0) ? 0 : sm[t - 1];   // exclusive
}

__global__ void scan_final(const int* __restrict__ deg, const int* __restrict__ bsum_ex,
                           int* __restrict__ off, int* __restrict__ cursor, int N, int E) {
  int base = blockIdx.x * SCAN_CHUNK + threadIdx.x * 8;
  int v[8], pre[8];
  int s = 0;
#pragma unroll
  for (int j = 0; j < 8; ++j) {
    int i = base + j;
    v[j] = (i < N) ? deg[i] : 0;
    pre[j] = s;
    s += v[j];
  }
  int lane = threadIdx.x & 63, w = threadIdx.x >> 6;
  int inc = s;
#pragma unroll
  for (int d = 1; d < 64; d <<= 1) {
    int u = __shfl_up(inc, d);
    if (lane >= d) inc += u;
  }
  __shared__ int wsum[4], woff[4];
  if (lane == 63) wsum[w] = inc;
  __syncthreads();
  if (threadIdx.x == 0) {
    int r = 0;
    for (int q = 0; q < 4; ++q) { woff[q] = r; r += wsum[q]; }
  }
  __syncthreads();
  int ex = (inc - s) + woff[w] + bsum_ex[blockIdx.x];
#pragma unroll
  for (int j = 0; j < 8; ++j) {
    int i = base + j;
    if (i < N) {
      int o = ex + pre[j];
      off[i] = o;
      cursor[i] = o;
    }
  }
  if (blockIdx.x == 0 && threadIdx.x == 0) off[N] = E;
}

__global__ void fill_csr(const int* __restrict__ src, const int* __restrict__ dst,
                         int* __restrict__ cursor, int* __restrict__ csr, int E) {
  int i = blockIdx.x * blockDim.x + threadIdx.x;
  if (i < E) {
    int p = atomicAdd(&cursor[dst[i]], 1);
    csr[p] = src[i];
  }
}

// ---------------- bf16 MFMA GEMM with per-row output scale, bf16 output ----------------
// C[m, 0:BN] = bf16((A[m, 0:KTOT] @ B) * scale[m]); BT is B transposed [BN][KTOT] bf16.
template<int BM, int BN, int KTOT, int WM, int WN>
__global__ __launch_bounds__(256) void mfma_gemm_scale(
    const ushort* __restrict__ A, const ushort* __restrict__ BT,
    const float* __restrict__ scale, ushort* __restrict__ C, int M) {
  constexpr int BK = 64;
  constexpr int FM = (BM / WM) / 16;
  constexpr int FN = (BN / WN) / 16;
  constexpr int ABYTES = BM * BK * 2;
  constexpr int BBYTES = BN * BK * 2;
  __shared__ char lds[ABYTES + BBYTES];
  char* Asm = lds;
  char* Bsm = lds + ABYTES;

  const int tid = threadIdx.x;
  const int lane = tid & 63;
  const int w = tid >> 6;
  const int wm = w / WN, wn = w % WN;
  const int m0 = blockIdx.x * BM;

  f32x4 acc[FM][FN];
#pragma unroll
  for (int m = 0; m < FM; ++m)
#pragma unroll
    for (int n = 0; n < FN; ++n) acc[m][n] = (f32x4){0.f, 0.f, 0.f, 0.f};

  const int ra = lane & 15;   // A-row / B-col within 16
  const int kg = lane >> 4;   // k-group (8 bf16 = 16B each)

  for (int kt = 0; kt < KTOT / BK; ++kt) {
    // ---- stage A tile [BM][BK] (pre-swizzled source, linear LDS dest) ----
#pragma unroll
    for (int s = 0; s < ABYTES / 4096; ++s) {
      int L = s * 4096 + tid * 16;
      int r = L >> 7;
      int slot = (L >> 4) & 7;
      int gr = m0 + r; if (gr >= M) gr = M - 1;
      const char* gp = (const char*)A + (size_t)gr * (KTOT * 2) + kt * (BK * 2)
                     + ((slot * 16) ^ ((r & 7) << 4));
      __builtin_amdgcn_global_load_lds(
          (const __attribute__((address_space(1))) unsigned*)gp,
          (__attribute__((address_space(3))) unsigned*)(Asm + L), 16, 0, 0);
    }
    // ---- stage B tile [BN][BK] ----
#pragma unroll
    for (int s = 0; s < BBYTES / 4096; ++s) {
      int L = s * 4096 + tid * 16;
      int r = L >> 7;
      int slot = (L >> 4) & 7;
      const char* gp = (const char*)BT + (size_t)r * (KTOT * 2) + kt * (BK * 2)
                     + ((slot * 16) ^ ((r & 7) << 4));
      __builtin_amdgcn_global_load_lds(
          (const __attribute__((address_space(1))) unsigned*)gp,
          (__attribute__((address_space(3))) unsigned*)(Bsm + L), 16, 0, 0);
    }
    __syncthreads();   // drains vmcnt + lgkmcnt

    // ---- compute: 2 k-substeps of 32 ----
#pragma unroll
    for (int ks = 0; ks < 2; ++ks) {
      bf16x8 af[FM], bfr[FN];
#pragma unroll
      for (int m = 0; m < FM; ++m) {
        int r = wm * (BM / WM) + m * 16 + ra;
        int cb = ks * 64 + kg * 16;
        af[m] = *(const bf16x8*)(Asm + r * 128 + (cb ^ ((r & 7) << 4)));
      }
#pragma unroll
      for (int n = 0; n < FN; ++n) {
        int c = wn * (BN / WN) + n * 16 + ra;
        int cb = ks * 64 + kg * 16;
        bfr[n] = *(const bf16x8*)(Bsm + c * 128 + (cb ^ ((c & 7) << 4)));
      }
#pragma unroll
      for (int m = 0; m < FM; ++m)
#pragma unroll
        for (int n = 0; n < FN; ++n)
          acc[m][n] = __builtin_amdgcn_mfma_f32_16x16x32_bf16(af[m], bfr[n], acc[m][n], 0, 0, 0);
    }
    __syncthreads();
  }

  // ---- epilogue: scale by norm_src, write bf16 ----
#pragma unroll
  for (int m = 0; m < FM; ++m) {
#pragma unroll
    for (int j = 0; j < 4; ++j) {
      int rl = wm * (BM / WM) + m * 16 + (lane >> 4) * 4 + j;
      int gr = m0 + rl;
      if (gr < M) {
        float sc = scale[gr];
#pragma unroll
        for (int n = 0; n < FN; ++n) {
          int c = wn * (BN / WN) + n * 16 + (lane & 15);
          C[(size_t)gr * BN + c] = f2bf(acc[m][n][j] * sc);
        }
      }
    }
  }
}

// ---------------- gathers ----------------
// x2[n,:] = bf16(relu(nd[n]*sum_{e in in(n)} h1[src_e,:] + b1)); h1 is bf16 [N][128]
__global__ void gather1(const ushort* __restrict__ h1, const int* __restrict__ off,
                        const int* __restrict__ csr, const float* __restrict__ nd,
                        const float* __restrict__ b1, ushort* __restrict__ x2, int N) {
  int w = (blockIdx.x * blockDim.x + threadIdx.x) >> 6;
  int lane = threadIdx.x & 63;
  if (w >= N) return;
  int lo = off[w], hi = off[w + 1];
  const unsigned* h = (const unsigned*)h1;   // 128 bf16 = 64 uints per row
  float sx = 0.f, sy = 0.f;
  for (int j = lo; j < hi; ++j) {
    int s = csr[j];
    unsigned u = h[(size_t)s * 64 + lane];
    sx += __builtin_bit_cast(float, u << 16);
    sy += __builtin_bit_cast(float, u & 0xFFFF0000u);
  }
  float sc = nd[w];
  float2 bb = ((const float2*)b1)[lane];
  float ox = fmaxf(sx * sc + bb.x, 0.f);
  float oy = fmaxf(sy * sc + bb.y, 0.f);
  ushort2 o; o.x = f2bf(ox); o.y = f2bf(oy);
  ((ushort2*)x2)[(size_t)w * 64 + lane] = o;
}

// out[n,:] = sigmoid(nd[n]*sum h2[src,:] + b2); h2 is bf16 [N][64]
__global__ void gather2(const ushort* __restrict__ h2, const int* __restrict__ off,
                        const int* __restrict__ csr, const float* __restrict__ nd,
                        const float* __restrict__ b2, float* __restrict__ out, int N) {
  int w = (blockIdx.x * blockDim.x + threadIdx.x) >> 6;
  int lane = threadIdx.x & 63;
  if (w >= N) return;
  int lo = off[w], hi = off[w + 1];
  float s = 0.f;
  for (int j = lo; j < hi; ++j) {
    int sr = csr[j];
    s += bf2f(h2[(size_t)sr * 64 + lane]);
  }
  float v = s * nd[w] + b2[lane];
  out[(size_t)w * 64 + lane] = 1.f / (1.f + expf(-v));
}

extern "C" void kernel_launch(void* const* d_in, const int* in_sizes, int n_in,
                              void* d_out, int out_size, void* d_ws, size_t ws_size,
                              hipStream_t stream) {
  const float* feat = (const float*)d_in[0];
  const int*   src  = (const int*)d_in[1];
  const int*   dst  = (const int*)d_in[2];
  const float* W1   = (const float*)d_in[3];
  const float* b1   = (const float*)d_in[4];
  const float* W2   = (const float*)d_in[5];
  const float* b2   = (const float*)d_in[6];
  float* out = (float*)d_out;

  const int N = in_sizes[0] / IN_F;   // 100000
  const int E = in_sizes[1];          // 1600000

  size_t off = 0;
  auto alloc = [&](size_t bytes) -> void* {
    void* p = (char*)d_ws + off;
    off = (off + bytes + 255) & ~(size_t)255;
    return p;
  };
  int*    deg_s   = (int*)alloc((size_t)N * 4);
  int*    deg_d   = (int*)alloc((size_t)N * 4);
  float*  norm_s  = (float*)alloc((size_t)N * 4);
  float*  norm_d  = (float*)alloc((size_t)N * 4);
  int*    row_off = (int*)alloc((size_t)(N + 1) * 4);
  int*    cursor  = (int*)alloc((size_t)N * 4);
  int*    bsum    = (int*)alloc((size_t)1024 * 4);
  int*    csr     = (int*)alloc((size_t)E * 4);
  ushort* featbf  = (ushort*)alloc((size_t)N * IN_F * 2);
  ushort* w1t     = (ushort*)alloc((size_t)H_F * IN_F * 2);
  ushort* w2t     = (ushort*)alloc((size_t)N_CLS * H_F * 2);
  ushort* h1      = (ushort*)alloc((size_t)N * H_F * 2);   // bf16
  ushort* x2bf    = (ushort*)alloc((size_t)N * H_F * 2);
  ushort* h2      = (ushort*)alloc((size_t)N * N_CLS * 2); // bf16
  (void)ws_size;

  hipMemsetAsync(deg_s, 0, (size_t)N * 4, stream);
  hipMemsetAsync(deg_d, 0, (size_t)N * 4, stream);

  conv_feat<<<2048, 256, 0, stream>>>(feat, featbf, N * IN_F / 4);
  conv_wT<<<(IN_F * H_F + 255) / 256, 256, 0, stream>>>(W1, w1t, IN_F, H_F);
  conv_wT<<<(H_F * N_CLS + 255) / 256, 256, 0, stream>>>(W2, w2t, H_F, N_CLS);

  deg_kernel<<<(E + 255) / 256, 256, 0, stream>>>(src, dst, deg_s, deg_d, E);
  norm_kernel<<<(N + 255) / 256, 256, 0, stream>>>(deg_s, deg_d, norm_s, norm_d, N);

  const int NB = (N + SCAN_CHUNK - 1) / SCAN_CHUNK;   // 49
  scan_part<<<NB, 256, 0, stream>>>(deg_d, bsum, N);
  scan_bsum<<<1, 1024, 0, stream>>>(bsum, NB);
  scan_final<<<NB, 256, 0, stream>>>(deg_d, bsum, row_off, cursor, N, E);
  fill_csr<<<(E + 255) / 256, 256, 0, stream>>>(src, dst, cursor, csr, E);

  // layer 1: h1 = bf16((feat @ W1) * norm_src)   [bf16 MFMA]
  mfma_gemm_scale<128, 128, 256, 2, 2><<<(N + 127) / 128, 256, 0, stream>>>(
      featbf, w1t, norm_s, h1, N);
  gather1<<<(N * 64 + 255) / 256, 256, 0, stream>>>(h1, row_off, csr, norm_d, b1, x2bf, N);

  // layer 2: h2 = bf16((x2 @ W2) * norm_src)   [bf16 MFMA]
  mfma_gemm_scale<128, 64, 128, 2, 2><<<(N + 127) / 128, 256, 0, stream>>>(
      x2bf, w2t, norm_s, h2, N);
  gather2<<<(N * 64 + 255) / 256, 256, 0, stream>>>(h2, row_off, csr, norm_d, b2, out, N);
}

// Round 5
// 435.657 us; speedup vs baseline: 2.5310x; 1.4223x over previous
//
#include <hip/hip_runtime.h>
#include <cmath>

#define IN_F 256
#define H_F  128
#define N_CLS 64
#define SCAN_CHUNK 2048   // 256 threads * 8 elems

typedef __attribute__((ext_vector_type(8))) short bf16x8;
typedef __attribute__((ext_vector_type(4))) float f32x4;

__device__ __forceinline__ ushort f2bf(float x) {
  unsigned b = __builtin_bit_cast(unsigned, x);
  b += 0x7FFF + ((b >> 16) & 1);          // RNE
  return (ushort)(b >> 16);
}
__device__ __forceinline__ float bf2f(ushort u) {
  unsigned b = ((unsigned)u) << 16;
  return __builtin_bit_cast(float, b);
}

// ---------------- bf16 conversion kernels ----------------
__global__ void conv_feat(const float* __restrict__ in, ushort* __restrict__ out, int n4) {
  int i = blockIdx.x * blockDim.x + threadIdx.x;
  int stride = gridDim.x * blockDim.x;
  for (; i < n4; i += stride) {
    float4 v = ((const float4*)in)[i];
    ushort4 o;
    o.x = f2bf(v.x); o.y = f2bf(v.y); o.z = f2bf(v.z); o.w = f2bf(v.w);
    ((ushort4*)out)[i] = o;
  }
}

// WT[n][k] = bf16(W[k][n])  (tiny)
__global__ void conv_wT(const float* __restrict__ W, ushort* __restrict__ WT, int K, int N) {
  int i = blockIdx.x * blockDim.x + threadIdx.x;
  if (i >= K * N) return;
  int k = i / N, n = i % N;
  WT[n * K + k] = f2bf(W[i]);
}

// ---------------- degree + norm ----------------
__global__ void deg_kernel(const int* __restrict__ src, const int* __restrict__ dst,
                           int* __restrict__ degs, int* __restrict__ degd, int E) {
  int i = blockIdx.x * blockDim.x + threadIdx.x;
  if (i < E) {
    atomicAdd(&degs[src[i]], 1);
    atomicAdd(&degd[dst[i]], 1);
  }
}

__global__ void norm_kernel(const int* __restrict__ degs, const int* __restrict__ degd,
                            float* __restrict__ ns, float* __restrict__ nd, int N) {
  int i = blockIdx.x * blockDim.x + threadIdx.x;
  if (i < N) {
    int a = degs[i], b = degd[i];
    ns[i] = a > 0 ? rsqrtf((float)a) : 0.f;
    nd[i] = b > 0 ? rsqrtf((float)b) : 0.f;
  }
}

// ---------------- CSR build: 3-kernel decoupled scan ----------------
__global__ void scan_part(const int* __restrict__ deg, int* __restrict__ bsum, int N) {
  int base = blockIdx.x * SCAN_CHUNK + threadIdx.x * 8;
  int s = 0;
#pragma unroll
  for (int j = 0; j < 8; ++j) {
    int i = base + j;
    if (i < N) s += deg[i];
  }
#pragma unroll
  for (int d = 1; d < 64; d <<= 1) s += __shfl_xor(s, d);
  __shared__ int ws[4];
  int lane = threadIdx.x & 63, w = threadIdx.x >> 6;
  if (lane == 0) ws[w] = s;
  __syncthreads();
  if (threadIdx.x == 0) bsum[blockIdx.x] = ws[0] + ws[1] + ws[2] + ws[3];
}

__global__ __launch_bounds__(1024) void scan_bsum(int* __restrict__ bsum, int nb) {
  __shared__ int sm[1024];
  int t = threadIdx.x;
  sm[t] = (t < nb) ? bsum[t] : 0;
  __syncthreads();
  for (int d = 1; d < 1024; d <<= 1) {
    int v = (t >= d) ? sm[t - d] : 0;
    __syncthreads();
    sm[t] += v;
    __syncthreads();
  }
  if (t < nb) bsum[t] = (t == 0) ? 0 : sm[t - 1];   // exclusive
}

__global__ void scan_final(const int* __restrict__ deg, const int* __restrict__ bsum_ex,
                           int* __restrict__ off, int* __restrict__ cursor, int N, int E) {
  int base = blockIdx.x * SCAN_CHUNK + threadIdx.x * 8;
  int v[8], pre[8];
  int s = 0;
#pragma unroll
  for (int j = 0; j < 8; ++j) {
    int i = base + j;
    v[j] = (i < N) ? deg[i] : 0;
    pre[j] = s;
    s += v[j];
  }
  int lane = threadIdx.x & 63, w = threadIdx.x >> 6;
  int inc = s;
#pragma unroll
  for (int d = 1; d < 64; d <<= 1) {
    int u = __shfl_up(inc, d);
    if (lane >= d) inc += u;
  }
  __shared__ int wsum[4], woff[4];
  if (lane == 63) wsum[w] = inc;
  __syncthreads();
  if (threadIdx.x == 0) {
    int r = 0;
    for (int q = 0; q < 4; ++q) { woff[q] = r; r += wsum[q]; }
  }
  __syncthreads();
  int ex = (inc - s) + woff[w] + bsum_ex[blockIdx.x];
#pragma unroll
  for (int j = 0; j < 8; ++j) {
    int i = base + j;
    if (i < N) {
      int o = ex + pre[j];
      off[i] = o;
      cursor[i] = o;
    }
  }
  if (blockIdx.x == 0 && threadIdx.x == 0) off[N] = E;
}

__global__ void fill_csr(const int* __restrict__ src, const int* __restrict__ dst,
                         int* __restrict__ cursor, int* __restrict__ csr, int E) {
  int i = blockIdx.x * blockDim.x + threadIdx.x;
  if (i < E) {
    int p = atomicAdd(&cursor[dst[i]], 1);
    csr[p] = src[i];
  }
}

// ---------------- bf16 MFMA GEMM with per-row output scale, bf16 output ----------------
// C[m, 0:BN] = bf16((A[m, 0:KTOT] @ B) * scale[m]); BT is B transposed [BN][KTOT] bf16.
template<int BM, int BN, int KTOT, int WM, int WN>
__global__ __launch_bounds__(256) void mfma_gemm_scale(
    const ushort* __restrict__ A, const ushort* __restrict__ BT,
    const float* __restrict__ scale, ushort* __restrict__ C, int M) {
  constexpr int BK = 64;
  constexpr int FM = (BM / WM) / 16;
  constexpr int FN = (BN / WN) / 16;
  constexpr int ABYTES = BM * BK * 2;
  constexpr int BBYTES = BN * BK * 2;
  __shared__ char lds[ABYTES + BBYTES];
  char* Asm = lds;
  char* Bsm = lds + ABYTES;

  const int tid = threadIdx.x;
  const int lane = tid & 63;
  const int w = tid >> 6;
  const int wm = w / WN, wn = w % WN;
  const int m0 = blockIdx.x * BM;

  f32x4 acc[FM][FN];
#pragma unroll
  for (int m = 0; m < FM; ++m)
#pragma unroll
    for (int n = 0; n < FN; ++n) acc[m][n] = (f32x4){0.f, 0.f, 0.f, 0.f};

  const int ra = lane & 15;   // A-row / B-col within 16
  const int kg = lane >> 4;   // k-group (8 bf16 = 16B each)

  for (int kt = 0; kt < KTOT / BK; ++kt) {
    // ---- stage A tile [BM][BK] (pre-swizzled source, linear LDS dest) ----
#pragma unroll
    for (int s = 0; s < ABYTES / 4096; ++s) {
      int L = s * 4096 + tid * 16;
      int r = L >> 7;
      int slot = (L >> 4) & 7;
      int gr = m0 + r; if (gr >= M) gr = M - 1;
      const char* gp = (const char*)A + (size_t)gr * (KTOT * 2) + kt * (BK * 2)
                     + ((slot * 16) ^ ((r & 7) << 4));
      __builtin_amdgcn_global_load_lds(
          (const __attribute__((address_space(1))) unsigned*)gp,
          (__attribute__((address_space(3))) unsigned*)(Asm + L), 16, 0, 0);
    }
    // ---- stage B tile [BN][BK] ----
#pragma unroll
    for (int s = 0; s < BBYTES / 4096; ++s) {
      int L = s * 4096 + tid * 16;
      int r = L >> 7;
      int slot = (L >> 4) & 7;
      const char* gp = (const char*)BT + (size_t)r * (KTOT * 2) + kt * (BK * 2)
                     + ((slot * 16) ^ ((r & 7) << 4));
      __builtin_amdgcn_global_load_lds(
          (const __attribute__((address_space(1))) unsigned*)gp,
          (__attribute__((address_space(3))) unsigned*)(Bsm + L), 16, 0, 0);
    }
    __syncthreads();   // drains vmcnt + lgkmcnt

    // ---- compute: 2 k-substeps of 32 ----
#pragma unroll
    for (int ks = 0; ks < 2; ++ks) {
      bf16x8 af[FM], bfr[FN];
#pragma unroll
      for (int m = 0; m < FM; ++m) {
        int r = wm * (BM / WM) + m * 16 + ra;
        int cb = ks * 64 + kg * 16;
        af[m] = *(const bf16x8*)(Asm + r * 128 + (cb ^ ((r & 7) << 4)));
      }
#pragma unroll
      for (int n = 0; n < FN; ++n) {
        int c = wn * (BN / WN) + n * 16 + ra;
        int cb = ks * 64 + kg * 16;
        bfr[n] = *(const bf16x8*)(Bsm + c * 128 + (cb ^ ((c & 7) << 4)));
      }
#pragma unroll
      for (int m = 0; m < FM; ++m)
#pragma unroll
        for (int n = 0; n < FN; ++n)
          acc[m][n] = __builtin_amdgcn_mfma_f32_16x16x32_bf16(af[m], bfr[n], acc[m][n], 0, 0, 0);
    }
    __syncthreads();
  }

  // ---- epilogue: scale by norm_src, write bf16 ----
#pragma unroll
  for (int m = 0; m < FM; ++m) {
#pragma unroll
    for (int j = 0; j < 4; ++j) {
      int rl = wm * (BM / WM) + m * 16 + (lane >> 4) * 4 + j;
      int gr = m0 + rl;
      if (gr < M) {
        float sc = scale[gr];
#pragma unroll
        for (int n = 0; n < FN; ++n) {
          int c = wn * (BN / WN) + n * 16 + (lane & 15);
          C[(size_t)gr * BN + c] = f2bf(acc[m][n][j] * sc);
        }
      }
    }
  }
}

// ---------------- gathers ----------------
// x2[n,:] = bf16(relu(nd[n]*sum_{e in in(n)} h1[src_e,:] + b1)); h1 is bf16 [N][128]
// One wave per node; edge loop unrolled x8 for memory-level parallelism.
__global__ void gather1(const ushort* __restrict__ h1, const int* __restrict__ off,
                        const int* __restrict__ csr, const float* __restrict__ nd,
                        const float* __restrict__ b1, ushort* __restrict__ x2, int N) {
  int w = (blockIdx.x * blockDim.x + threadIdx.x) >> 6;
  int lane = threadIdx.x & 63;
  if (w >= N) return;
  int lo = off[w], hi = off[w + 1];
  const unsigned* h = (const unsigned*)h1;   // 128 bf16 = 64 uints per row
  float sx = 0.f, sy = 0.f;
#define ACC1(u) { sx += __builtin_bit_cast(float, (u) << 16); \
                  sy += __builtin_bit_cast(float, (u) & 0xFFFF0000u); }
  int j = lo;
  for (; j + 8 <= hi; j += 8) {
    int s0 = csr[j+0], s1 = csr[j+1], s2 = csr[j+2], s3 = csr[j+3];
    int s4 = csr[j+4], s5 = csr[j+5], s6 = csr[j+6], s7 = csr[j+7];
    unsigned u0 = h[(size_t)s0 * 64 + lane];
    unsigned u1 = h[(size_t)s1 * 64 + lane];
    unsigned u2 = h[(size_t)s2 * 64 + lane];
    unsigned u3 = h[(size_t)s3 * 64 + lane];
    unsigned u4 = h[(size_t)s4 * 64 + lane];
    unsigned u5 = h[(size_t)s5 * 64 + lane];
    unsigned u6 = h[(size_t)s6 * 64 + lane];
    unsigned u7 = h[(size_t)s7 * 64 + lane];
    ACC1(u0) ACC1(u1) ACC1(u2) ACC1(u3) ACC1(u4) ACC1(u5) ACC1(u6) ACC1(u7)
  }
  for (; j + 4 <= hi; j += 4) {
    int s0 = csr[j+0], s1 = csr[j+1], s2 = csr[j+2], s3 = csr[j+3];
    unsigned u0 = h[(size_t)s0 * 64 + lane];
    unsigned u1 = h[(size_t)s1 * 64 + lane];
    unsigned u2 = h[(size_t)s2 * 64 + lane];
    unsigned u3 = h[(size_t)s3 * 64 + lane];
    ACC1(u0) ACC1(u1) ACC1(u2) ACC1(u3)
  }
  for (; j < hi; ++j) {
    int s = csr[j];
    unsigned u = h[(size_t)s * 64 + lane];
    ACC1(u)
  }
#undef ACC1
  float sc = nd[w];
  float2 bb = ((const float2*)b1)[lane];
  float ox = fmaxf(sx * sc + bb.x, 0.f);
  float oy = fmaxf(sy * sc + bb.y, 0.f);
  ushort2 o; o.x = f2bf(ox); o.y = f2bf(oy);
  ((ushort2*)x2)[(size_t)w * 64 + lane] = o;
}

// out[n,:] = sigmoid(nd[n]*sum h2[src,:] + b2); h2 is bf16 [N][64]
// TWO nodes per wave (one per 32-lane half), uint loads, edge loop unrolled x8.
__global__ void gather2(const ushort* __restrict__ h2, const int* __restrict__ off,
                        const int* __restrict__ csr, const float* __restrict__ nd,
                        const float* __restrict__ b2, float* __restrict__ out, int N) {
  int wv = (blockIdx.x * blockDim.x + threadIdx.x) >> 6;
  int lane = threadIdx.x & 63;
  int grp = lane >> 5;        // which node of the pair
  int sub = lane & 31;        // uint column (2 features)
  int node = wv * 2 + grp;
  if (node >= N) return;
  int lo = off[node], hi = off[node + 1];
  const unsigned* h = (const unsigned*)h2;   // 64 bf16 = 32 uints per row
  float s0 = 0.f, s1 = 0.f;
#define ACC2(u) { s0 += __builtin_bit_cast(float, (u) << 16); \
                  s1 += __builtin_bit_cast(float, (u) & 0xFFFF0000u); }
  int j = lo;
  for (; j + 8 <= hi; j += 8) {
    int i0 = csr[j+0], i1 = csr[j+1], i2 = csr[j+2], i3 = csr[j+3];
    int i4 = csr[j+4], i5 = csr[j+5], i6 = csr[j+6], i7 = csr[j+7];
    unsigned u0 = h[(size_t)i0 * 32 + sub];
    unsigned u1 = h[(size_t)i1 * 32 + sub];
    unsigned u2 = h[(size_t)i2 * 32 + sub];
    unsigned u3 = h[(size_t)i3 * 32 + sub];
    unsigned u4 = h[(size_t)i4 * 32 + sub];
    unsigned u5 = h[(size_t)i5 * 32 + sub];
    unsigned u6 = h[(size_t)i6 * 32 + sub];
    unsigned u7 = h[(size_t)i7 * 32 + sub];
    ACC2(u0) ACC2(u1) ACC2(u2) ACC2(u3) ACC2(u4) ACC2(u5) ACC2(u6) ACC2(u7)
  }
  for (; j + 4 <= hi; j += 4) {
    int i0 = csr[j+0], i1 = csr[j+1], i2 = csr[j+2], i3 = csr[j+3];
    unsigned u0 = h[(size_t)i0 * 32 + sub];
    unsigned u1 = h[(size_t)i1 * 32 + sub];
    unsigned u2 = h[(size_t)i2 * 32 + sub];
    unsigned u3 = h[(size_t)i3 * 32 + sub];
    ACC2(u0) ACC2(u1) ACC2(u2) ACC2(u3)
  }
  for (; j < hi; ++j) {
    int i0 = csr[j];
    unsigned u = h[(size_t)i0 * 32 + sub];
    ACC2(u)
  }
#undef ACC2
  float scn = nd[node];
  float2 bb = ((const float2*)b2)[sub];
  float v0 = s0 * scn + bb.x;
  float v1 = s1 * scn + bb.y;
  float2 o;
  o.x = 1.f / (1.f + expf(-v0));
  o.y = 1.f / (1.f + expf(-v1));
  ((float2*)out)[(size_t)node * 32 + sub] = o;
}

extern "C" void kernel_launch(void* const* d_in, const int* in_sizes, int n_in,
                              void* d_out, int out_size, void* d_ws, size_t ws_size,
                              hipStream_t stream) {
  const float* feat = (const float*)d_in[0];
  const int*   src  = (const int*)d_in[1];
  const int*   dst  = (const int*)d_in[2];
  const float* W1   = (const float*)d_in[3];
  const float* b1   = (const float*)d_in[4];
  const float* W2   = (const float*)d_in[5];
  const float* b2   = (const float*)d_in[6];
  float* out = (float*)d_out;

  const int N = in_sizes[0] / IN_F;   // 100000
  const int E = in_sizes[1];          // 1600000

  size_t off = 0;
  auto alloc = [&](size_t bytes) -> void* {
    void* p = (char*)d_ws + off;
    off = (off + bytes + 255) & ~(size_t)255;
    return p;
  };
  int*    deg_s   = (int*)alloc((size_t)N * 4);
  int*    deg_d   = (int*)alloc((size_t)N * 4);
  float*  norm_s  = (float*)alloc((size_t)N * 4);
  float*  norm_d  = (float*)alloc((size_t)N * 4);
  int*    row_off = (int*)alloc((size_t)(N + 1) * 4);
  int*    cursor  = (int*)alloc((size_t)N * 4);
  int*    bsum    = (int*)alloc((size_t)1024 * 4);
  int*    csr     = (int*)alloc((size_t)E * 4);
  ushort* featbf  = (ushort*)alloc((size_t)N * IN_F * 2);
  ushort* w1t     = (ushort*)alloc((size_t)H_F * IN_F * 2);
  ushort* w2t     = (ushort*)alloc((size_t)N_CLS * H_F * 2);
  ushort* h1      = (ushort*)alloc((size_t)N * H_F * 2);   // bf16
  ushort* x2bf    = (ushort*)alloc((size_t)N * H_F * 2);
  ushort* h2      = (ushort*)alloc((size_t)N * N_CLS * 2); // bf16
  (void)ws_size;

  hipMemsetAsync(deg_s, 0, (size_t)N * 4, stream);
  hipMemsetAsync(deg_d, 0, (size_t)N * 4, stream);

  conv_feat<<<2048, 256, 0, stream>>>(feat, featbf, N * IN_F / 4);
  conv_wT<<<(IN_F * H_F + 255) / 256, 256, 0, stream>>>(W1, w1t, IN_F, H_F);
  conv_wT<<<(H_F * N_CLS + 255) / 256, 256, 0, stream>>>(W2, w2t, H_F, N_CLS);

  deg_kernel<<<(E + 255) / 256, 256, 0, stream>>>(src, dst, deg_s, deg_d, E);
  norm_kernel<<<(N + 255) / 256, 256, 0, stream>>>(deg_s, deg_d, norm_s, norm_d, N);

  const int NB = (N + SCAN_CHUNK - 1) / SCAN_CHUNK;   // 49
  scan_part<<<NB, 256, 0, stream>>>(deg_d, bsum, N);
  scan_bsum<<<1, 1024, 0, stream>>>(bsum, NB);
  scan_final<<<NB, 256, 0, stream>>>(deg_d, bsum, row_off, cursor, N, E);
  fill_csr<<<(E + 255) / 256, 256, 0, stream>>>(src, dst, cursor, csr, E);

  // layer 1: h1 = bf16((feat @ W1) * norm_src)   [bf16 MFMA]
  mfma_gemm_scale<128, 128, 256, 2, 2><<<(N + 127) / 128, 256, 0, stream>>>(
      featbf, w1t, norm_s, h1, N);
  gather1<<<(N * 64 + 255) / 256, 256, 0, stream>>>(h1, row_off, csr, norm_d, b1, x2bf, N);

  // layer 2: h2 = bf16((x2 @ W2) * norm_src)   [bf16 MFMA]
  mfma_gemm_scale<128, 64, 128, 2, 2><<<(N + 127) / 128, 256, 0, stream>>>(
      x2bf, w2t, norm_s, h2, N);
  int pairs = (N + 1) / 2;
  gather2<<<(pairs * 64 + 255) / 256, 256, 0, stream>>>(h2, row_off, csr, norm_d, b2, out, N);
}

// Round 6
// 430.560 us; speedup vs baseline: 2.5609x; 1.0118x over previous
//
#include <hip/hip_runtime.h>
#include <cmath>

#define IN_F 256
#define H_F  128
#define N_CLS 64
#define SCAN_CHUNK 2048   // 256 threads * 8 elems
#define NXCD 8

typedef __attribute__((ext_vector_type(8))) short bf16x8;
typedef __attribute__((ext_vector_type(4))) float f32x4;

__device__ __forceinline__ ushort f2bf(float x) {
  unsigned b = __builtin_bit_cast(unsigned, x);
  b += 0x7FFF + ((b >> 16) & 1);          // RNE
  return (ushort)(b >> 16);
}

// ---------------- bf16 conversion kernels ----------------
__global__ void conv_feat(const float* __restrict__ in, ushort* __restrict__ out, int n4) {
  int i = blockIdx.x * blockDim.x + threadIdx.x;
  int stride = gridDim.x * blockDim.x;
  for (; i < n4; i += stride) {
    float4 v = ((const float4*)in)[i];
    ushort4 o;
    o.x = f2bf(v.x); o.y = f2bf(v.y); o.z = f2bf(v.z); o.w = f2bf(v.w);
    ((ushort4*)out)[i] = o;
  }
}

// WT[n][k] = bf16(W[k][n])  (tiny)
__global__ void conv_wT(const float* __restrict__ W, ushort* __restrict__ WT, int K, int N) {
  int i = blockIdx.x * blockDim.x + threadIdx.x;
  if (i >= K * N) return;
  int k = i / N, n = i % N;
  WT[n * K + k] = f2bf(W[i]);
}

// ---------------- degree histogram, 8-way XCD-privatized ----------------
// blockIdx.x & 7 ~= resident XCD (round-robin dispatch): atomics stay in the
// local L2; no cross-XCD cache-line ping-pong.
__global__ void deg8_kernel(const int* __restrict__ src, const int* __restrict__ dst,
                            int* __restrict__ degs8, int* __restrict__ degc8,
                            int N, int E) {
  int i = blockIdx.x * blockDim.x + threadIdx.x;
  int part = blockIdx.x & (NXCD - 1);
  if (i < E) {
    atomicAdd(&degs8[part * N + src[i]], 1);
    atomicAdd(&degc8[part * N + dst[i]], 1);
  }
}

// deg_s/deg_d = sum over 8 copies; norms; deg_d also feeds the scan.
__global__ void reduce_norm(const int* __restrict__ degs8, const int* __restrict__ degc8,
                            float* __restrict__ ns, float* __restrict__ nd,
                            int* __restrict__ deg_d, int N) {
  int i = blockIdx.x * blockDim.x + threadIdx.x;
  if (i >= N) return;
  int a = 0, b = 0;
#pragma unroll
  for (int k = 0; k < NXCD; ++k) {
    a += degs8[k * N + i];
    b += degc8[k * N + i];
  }
  ns[i] = a > 0 ? rsqrtf((float)a) : 0.f;
  nd[i] = b > 0 ? rsqrtf((float)b) : 0.f;
  deg_d[i] = b;
}

// ---------------- CSR build: 3-kernel decoupled scan ----------------
__global__ void scan_part(const int* __restrict__ deg, int* __restrict__ bsum, int N) {
  int base = blockIdx.x * SCAN_CHUNK + threadIdx.x * 8;
  int s = 0;
#pragma unroll
  for (int j = 0; j < 8; ++j) {
    int i = base + j;
    if (i < N) s += deg[i];
  }
#pragma unroll
  for (int d = 1; d < 64; d <<= 1) s += __shfl_xor(s, d);
  __shared__ int ws[4];
  int lane = threadIdx.x & 63, w = threadIdx.x >> 6;
  if (lane == 0) ws[w] = s;
  __syncthreads();
  if (threadIdx.x == 0) bsum[blockIdx.x] = ws[0] + ws[1] + ws[2] + ws[3];
}

__global__ __launch_bounds__(1024) void scan_bsum(int* __restrict__ bsum, int nb) {
  __shared__ int sm[1024];
  int t = threadIdx.x;
  sm[t] = (t < nb) ? bsum[t] : 0;
  __syncthreads();
  for (int d = 1; d < 1024; d <<= 1) {
    int v = (t >= d) ? sm[t - d] : 0;
    __syncthreads();
    sm[t] += v;
    __syncthreads();
  }
  if (t < nb) bsum[t] = (t == 0) ? 0 : sm[t - 1];   // exclusive
}

__global__ void scan_final(const int* __restrict__ deg, const int* __restrict__ bsum_ex,
                           int* __restrict__ off, int N, int E) {
  int base = blockIdx.x * SCAN_CHUNK + threadIdx.x * 8;
  int v[8], pre[8];
  int s = 0;
#pragma unroll
  for (int j = 0; j < 8; ++j) {
    int i = base + j;
    v[j] = (i < N) ? deg[i] : 0;
    pre[j] = s;
    s += v[j];
  }
  int lane = threadIdx.x & 63, w = threadIdx.x >> 6;
  int inc = s;
#pragma unroll
  for (int d = 1; d < 64; d <<= 1) {
    int u = __shfl_up(inc, d);
    if (lane >= d) inc += u;
  }
  __shared__ int wsum[4], woff[4];
  if (lane == 63) wsum[w] = inc;
  __syncthreads();
  if (threadIdx.x == 0) {
    int r = 0;
    for (int q = 0; q < 4; ++q) { woff[q] = r; r += wsum[q]; }
  }
  __syncthreads();
  int ex = (inc - s) + woff[w] + bsum_ex[blockIdx.x];
#pragma unroll
  for (int j = 0; j < 8; ++j) {
    int i = base + j;
    if (i < N) off[i] = ex + pre[j];
  }
  if (blockIdx.x == 0 && threadIdx.x == 0) off[N] = E;
}

// cur8[k][i] = off[i] + sum_{k'<k} degc8[k'][i]  (per-XCD sub-list cursors)
__global__ void cursor_init(const int* __restrict__ degc8, const int* __restrict__ off,
                            int* __restrict__ cur8, int N) {
  int i = blockIdx.x * blockDim.x + threadIdx.x;
  if (i >= N) return;
  int run = off[i];
#pragma unroll
  for (int k = 0; k < NXCD; ++k) {
    cur8[k * N + i] = run;
    run += degc8[k * N + i];
  }
}

__global__ void fill_csr8(const int* __restrict__ src, const int* __restrict__ dst,
                          int* __restrict__ cur8, int* __restrict__ csr, int N, int E) {
  int i = blockIdx.x * blockDim.x + threadIdx.x;
  int part = blockIdx.x & (NXCD - 1);
  if (i < E) {
    int p = atomicAdd(&cur8[part * N + dst[i]], 1);
    csr[p] = src[i];
  }
}

// ---------------- bf16 MFMA GEMM with per-row output scale, bf16 output ----------------
// C[m, 0:BN] = bf16((A[m, 0:KTOT] @ B) * scale[m]); BT is B transposed [BN][KTOT] bf16.
template<int BM, int BN, int KTOT, int WM, int WN>
__global__ __launch_bounds__(256) void mfma_gemm_scale(
    const ushort* __restrict__ A, const ushort* __restrict__ BT,
    const float* __restrict__ scale, ushort* __restrict__ C, int M) {
  constexpr int BK = 64;
  constexpr int FM = (BM / WM) / 16;
  constexpr int FN = (BN / WN) / 16;
  constexpr int ABYTES = BM * BK * 2;
  constexpr int BBYTES = BN * BK * 2;
  __shared__ char lds[ABYTES + BBYTES];
  char* Asm = lds;
  char* Bsm = lds + ABYTES;

  const int tid = threadIdx.x;
  const int lane = tid & 63;
  const int w = tid >> 6;
  const int wm = w / WN, wn = w % WN;
  const int m0 = blockIdx.x * BM;

  f32x4 acc[FM][FN];
#pragma unroll
  for (int m = 0; m < FM; ++m)
#pragma unroll
    for (int n = 0; n < FN; ++n) acc[m][n] = (f32x4){0.f, 0.f, 0.f, 0.f};

  const int ra = lane & 15;   // A-row / B-col within 16
  const int kg = lane >> 4;   // k-group (8 bf16 = 16B each)

  for (int kt = 0; kt < KTOT / BK; ++kt) {
    // ---- stage A tile [BM][BK] (pre-swizzled source, linear LDS dest) ----
#pragma unroll
    for (int s = 0; s < ABYTES / 4096; ++s) {
      int L = s * 4096 + tid * 16;
      int r = L >> 7;
      int slot = (L >> 4) & 7;
      int gr = m0 + r; if (gr >= M) gr = M - 1;
      const char* gp = (const char*)A + (size_t)gr * (KTOT * 2) + kt * (BK * 2)
                     + ((slot * 16) ^ ((r & 7) << 4));
      __builtin_amdgcn_global_load_lds(
          (const __attribute__((address_space(1))) unsigned*)gp,
          (__attribute__((address_space(3))) unsigned*)(Asm + L), 16, 0, 0);
    }
    // ---- stage B tile [BN][BK] ----
#pragma unroll
    for (int s = 0; s < BBYTES / 4096; ++s) {
      int L = s * 4096 + tid * 16;
      int r = L >> 7;
      int slot = (L >> 4) & 7;
      const char* gp = (const char*)BT + (size_t)r * (KTOT * 2) + kt * (BK * 2)
                     + ((slot * 16) ^ ((r & 7) << 4));
      __builtin_amdgcn_global_load_lds(
          (const __attribute__((address_space(1))) unsigned*)gp,
          (__attribute__((address_space(3))) unsigned*)(Bsm + L), 16, 0, 0);
    }
    __syncthreads();   // drains vmcnt + lgkmcnt

    // ---- compute: 2 k-substeps of 32 ----
#pragma unroll
    for (int ks = 0; ks < 2; ++ks) {
      bf16x8 af[FM], bfr[FN];
#pragma unroll
      for (int m = 0; m < FM; ++m) {
        int r = wm * (BM / WM) + m * 16 + ra;
        int cb = ks * 64 + kg * 16;
        af[m] = *(const bf16x8*)(Asm + r * 128 + (cb ^ ((r & 7) << 4)));
      }
#pragma unroll
      for (int n = 0; n < FN; ++n) {
        int c = wn * (BN / WN) + n * 16 + ra;
        int cb = ks * 64 + kg * 16;
        bfr[n] = *(const bf16x8*)(Bsm + c * 128 + (cb ^ ((c & 7) << 4)));
      }
#pragma unroll
      for (int m = 0; m < FM; ++m)
#pragma unroll
        for (int n = 0; n < FN; ++n)
          acc[m][n] = __builtin_amdgcn_mfma_f32_16x16x32_bf16(af[m], bfr[n], acc[m][n], 0, 0, 0);
    }
    __syncthreads();
  }

  // ---- epilogue: scale by norm_src, write bf16 ----
#pragma unroll
  for (int m = 0; m < FM; ++m) {
#pragma unroll
    for (int j = 0; j < 4; ++j) {
      int rl = wm * (BM / WM) + m * 16 + (lane >> 4) * 4 + j;
      int gr = m0 + rl;
      if (gr < M) {
        float sc = scale[gr];
#pragma unroll
        for (int n = 0; n < FN; ++n) {
          int c = wn * (BN / WN) + n * 16 + (lane & 15);
          C[(size_t)gr * BN + c] = f2bf(acc[m][n][j] * sc);
        }
      }
    }
  }
}

// ---------------- gathers ----------------
// x2[n,:] = bf16(relu(nd[n]*sum_{e in in(n)} h1[src_e,:] + b1)); h1 is bf16 [N][128]
// One wave per node; edge loop unrolled x8 for memory-level parallelism.
__global__ void gather1(const ushort* __restrict__ h1, const int* __restrict__ off,
                        const int* __restrict__ csr, const float* __restrict__ nd,
                        const float* __restrict__ b1, ushort* __restrict__ x2, int N) {
  int w = (blockIdx.x * blockDim.x + threadIdx.x) >> 6;
  int lane = threadIdx.x & 63;
  if (w >= N) return;
  int lo = off[w], hi = off[w + 1];
  const unsigned* h = (const unsigned*)h1;   // 128 bf16 = 64 uints per row
  float sx = 0.f, sy = 0.f;
#define ACC1(u) { sx += __builtin_bit_cast(float, (u) << 16); \
                  sy += __builtin_bit_cast(float, (u) & 0xFFFF0000u); }
  int j = lo;
  for (; j + 8 <= hi; j += 8) {
    int s0 = csr[j+0], s1 = csr[j+1], s2 = csr[j+2], s3 = csr[j+3];
    int s4 = csr[j+4], s5 = csr[j+5], s6 = csr[j+6], s7 = csr[j+7];
    unsigned u0 = h[(size_t)s0 * 64 + lane];
    unsigned u1 = h[(size_t)s1 * 64 + lane];
    unsigned u2 = h[(size_t)s2 * 64 + lane];
    unsigned u3 = h[(size_t)s3 * 64 + lane];
    unsigned u4 = h[(size_t)s4 * 64 + lane];
    unsigned u5 = h[(size_t)s5 * 64 + lane];
    unsigned u6 = h[(size_t)s6 * 64 + lane];
    unsigned u7 = h[(size_t)s7 * 64 + lane];
    ACC1(u0) ACC1(u1) ACC1(u2) ACC1(u3) ACC1(u4) ACC1(u5) ACC1(u6) ACC1(u7)
  }
  for (; j + 4 <= hi; j += 4) {
    int s0 = csr[j+0], s1 = csr[j+1], s2 = csr[j+2], s3 = csr[j+3];
    unsigned u0 = h[(size_t)s0 * 64 + lane];
    unsigned u1 = h[(size_t)s1 * 64 + lane];
    unsigned u2 = h[(size_t)s2 * 64 + lane];
    unsigned u3 = h[(size_t)s3 * 64 + lane];
    ACC1(u0) ACC1(u1) ACC1(u2) ACC1(u3)
  }
  for (; j < hi; ++j) {
    int s = csr[j];
    unsigned u = h[(size_t)s * 64 + lane];
    ACC1(u)
  }
#undef ACC1
  float sc = nd[w];
  float2 bb = ((const float2*)b1)[lane];
  float ox = fmaxf(sx * sc + bb.x, 0.f);
  float oy = fmaxf(sy * sc + bb.y, 0.f);
  ushort2 o; o.x = f2bf(ox); o.y = f2bf(oy);
  ((ushort2*)x2)[(size_t)w * 64 + lane] = o;
}

// out[n,:] = sigmoid(nd[n]*sum h2[src,:] + b2); h2 is bf16 [N][64]
// TWO nodes per wave (one per 32-lane half), uint loads, edge loop unrolled x8.
__global__ void gather2(const ushort* __restrict__ h2, const int* __restrict__ off,
                        const int* __restrict__ csr, const float* __restrict__ nd,
                        const float* __restrict__ b2, float* __restrict__ out, int N) {
  int wv = (blockIdx.x * blockDim.x + threadIdx.x) >> 6;
  int lane = threadIdx.x & 63;
  int grp = lane >> 5;        // which node of the pair
  int sub = lane & 31;        // uint column (2 features)
  int node = wv * 2 + grp;
  if (node >= N) return;
  int lo = off[node], hi = off[node + 1];
  const unsigned* h = (const unsigned*)h2;   // 64 bf16 = 32 uints per row
  float s0 = 0.f, s1 = 0.f;
#define ACC2(u) { s0 += __builtin_bit_cast(float, (u) << 16); \
                  s1 += __builtin_bit_cast(float, (u) & 0xFFFF0000u); }
  int j = lo;
  for (; j + 8 <= hi; j += 8) {
    int i0 = csr[j+0], i1 = csr[j+1], i2 = csr[j+2], i3 = csr[j+3];
    int i4 = csr[j+4], i5 = csr[j+5], i6 = csr[j+6], i7 = csr[j+7];
    unsigned u0 = h[(size_t)i0 * 32 + sub];
    unsigned u1 = h[(size_t)i1 * 32 + sub];
    unsigned u2 = h[(size_t)i2 * 32 + sub];
    unsigned u3 = h[(size_t)i3 * 32 + sub];
    unsigned u4 = h[(size_t)i4 * 32 + sub];
    unsigned u5 = h[(size_t)i5 * 32 + sub];
    unsigned u6 = h[(size_t)i6 * 32 + sub];
    unsigned u7 = h[(size_t)i7 * 32 + sub];
    ACC2(u0) ACC2(u1) ACC2(u2) ACC2(u3) ACC2(u4) ACC2(u5) ACC2(u6) ACC2(u7)
  }
  for (; j + 4 <= hi; j += 4) {
    int i0 = csr[j+0], i1 = csr[j+1], i2 = csr[j+2], i3 = csr[j+3];
    unsigned u0 = h[(size_t)i0 * 32 + sub];
    unsigned u1 = h[(size_t)i1 * 32 + sub];
    unsigned u2 = h[(size_t)i2 * 32 + sub];
    unsigned u3 = h[(size_t)i3 * 32 + sub];
    ACC2(u0) ACC2(u1) ACC2(u2) ACC2(u3)
  }
  for (; j < hi; ++j) {
    int i0 = csr[j];
    unsigned u = h[(size_t)i0 * 32 + sub];
    ACC2(u)
  }
#undef ACC2
  float scn = nd[node];
  float2 bb = ((const float2*)b2)[sub];
  float v0 = s0 * scn + bb.x;
  float v1 = s1 * scn + bb.y;
  float2 o;
  o.x = 1.f / (1.f + expf(-v0));
  o.y = 1.f / (1.f + expf(-v1));
  ((float2*)out)[(size_t)node * 32 + sub] = o;
}

extern "C" void kernel_launch(void* const* d_in, const int* in_sizes, int n_in,
                              void* d_out, int out_size, void* d_ws, size_t ws_size,
                              hipStream_t stream) {
  const float* feat = (const float*)d_in[0];
  const int*   src  = (const int*)d_in[1];
  const int*   dst  = (const int*)d_in[2];
  const float* W1   = (const float*)d_in[3];
  const float* b1   = (const float*)d_in[4];
  const float* W2   = (const float*)d_in[5];
  const float* b2   = (const float*)d_in[6];
  float* out = (float*)d_out;

  const int N = in_sizes[0] / IN_F;   // 100000
  const int E = in_sizes[1];          // 1600000

  size_t off = 0;
  auto alloc = [&](size_t bytes) -> void* {
    void* p = (char*)d_ws + off;
    off = (off + bytes + 255) & ~(size_t)255;
    return p;
  };
  int*    degs8   = (int*)alloc((size_t)NXCD * N * 4);
  int*    degc8   = (int*)alloc((size_t)NXCD * N * 4);
  int*    cur8    = (int*)alloc((size_t)NXCD * N * 4);
  int*    deg_d   = (int*)alloc((size_t)N * 4);
  float*  norm_s  = (float*)alloc((size_t)N * 4);
  float*  norm_d  = (float*)alloc((size_t)N * 4);
  int*    row_off = (int*)alloc((size_t)(N + 1) * 4);
  int*    bsum    = (int*)alloc((size_t)1024 * 4);
  int*    csr     = (int*)alloc((size_t)E * 4);
  ushort* featbf  = (ushort*)alloc((size_t)N * IN_F * 2);
  ushort* w1t     = (ushort*)alloc((size_t)H_F * IN_F * 2);
  ushort* w2t     = (ushort*)alloc((size_t)N_CLS * H_F * 2);
  ushort* h1      = (ushort*)alloc((size_t)N * H_F * 2);   // bf16
  ushort* x2bf    = (ushort*)alloc((size_t)N * H_F * 2);
  ushort* h2      = (ushort*)alloc((size_t)N * N_CLS * 2); // bf16
  (void)ws_size;

  hipMemsetAsync(degs8, 0, (size_t)NXCD * N * 4, stream);
  hipMemsetAsync(degc8, 0, (size_t)NXCD * N * 4, stream);

  conv_feat<<<2048, 256, 0, stream>>>(feat, featbf, N * IN_F / 4);
  conv_wT<<<(IN_F * H_F + 255) / 256, 256, 0, stream>>>(W1, w1t, IN_F, H_F);
  conv_wT<<<(H_F * N_CLS + 255) / 256, 256, 0, stream>>>(W2, w2t, H_F, N_CLS);

  deg8_kernel<<<(E + 255) / 256, 256, 0, stream>>>(src, dst, degs8, degc8, N, E);
  reduce_norm<<<(N + 255) / 256, 256, 0, stream>>>(degs8, degc8, norm_s, norm_d, deg_d, N);

  const int NB = (N + SCAN_CHUNK - 1) / SCAN_CHUNK;   // 49
  scan_part<<<NB, 256, 0, stream>>>(deg_d, bsum, N);
  scan_bsum<<<1, 1024, 0, stream>>>(bsum, NB);
  scan_final<<<NB, 256, 0, stream>>>(deg_d, bsum, row_off, N, E);
  cursor_init<<<(N + 255) / 256, 256, 0, stream>>>(degc8, row_off, cur8, N);
  fill_csr8<<<(E + 255) / 256, 256, 0, stream>>>(src, dst, cur8, csr, N, E);

  // layer 1: h1 = bf16((feat @ W1) * norm_src)   [bf16 MFMA]
  mfma_gemm_scale<128, 128, 256, 2, 2><<<(N + 127) / 128, 256, 0, stream>>>(
      featbf, w1t, norm_s, h1, N);
  gather1<<<(N * 64 + 255) / 256, 256, 0, stream>>>(h1, row_off, csr, norm_d, b1, x2bf, N);

  // layer 2: h2 = bf16((x2 @ W2) * norm_src)   [bf16 MFMA]
  mfma_gemm_scale<128, 64, 128, 2, 2><<<(N + 127) / 128, 256, 0, stream>>>(
      x2bf, w2t, norm_s, h2, N);
  int pairs = (N + 1) / 2;
  gather2<<<(pairs * 64 + 255) / 256, 256, 0, stream>>>(h2, row_off, csr, norm_d, b2, out, N);
}

// Round 7
// 239.855 us; speedup vs baseline: 4.5971x; 1.7951x over previous
//
#include <hip/hip_runtime.h>
#include <cmath>

#define IN_F 256
#define H_F  128
#define N_CLS 64
#define SCAN_CHUNK 2048   // 256 threads * 8 elems
#define EPB 4096          // edges per block in sort kernels
#define MAXBK 400         // max coarse buckets (ceil(100096/256)=391)

typedef __attribute__((ext_vector_type(8))) short bf16x8;
typedef __attribute__((ext_vector_type(4))) float f32x4;

__device__ __forceinline__ ushort f2bf(float x) {
  unsigned b = __builtin_bit_cast(unsigned, x);
  b += 0x7FFF + ((b >> 16) & 1);          // RNE
  return (ushort)(b >> 16);
}

// ---------------- bf16 conversion kernels ----------------
__global__ void conv_feat(const float* __restrict__ in, ushort* __restrict__ out, int n4) {
  int i = blockIdx.x * blockDim.x + threadIdx.x;
  int stride = gridDim.x * blockDim.x;
  for (; i < n4; i += stride) {
    float4 v = ((const float4*)in)[i];
    ushort4 o;
    o.x = f2bf(v.x); o.y = f2bf(v.y); o.z = f2bf(v.z); o.w = f2bf(v.w);
    ((ushort4*)out)[i] = o;
  }
}

__global__ void conv_wT(const float* __restrict__ W, ushort* __restrict__ WT, int K, int N) {
  int i = blockIdx.x * blockDim.x + threadIdx.x;
  if (i >= K * N) return;
  int k = i / N, n = i % N;
  WT[n * K + k] = f2bf(W[i]);
}

// ---------------- graph build: atomic-free two-level counting sort ----------------
// Coarse bucket = node >> 8 (256 nodes/bucket). Per-(bucket,block) counts -> scan ->
// disjoint output ranges -> LDS-staged scatter (no global atomics at all).

// G1: per-block coarse histograms for dst and src.
__global__ __launch_bounds__(256) void hist_kernel(const int* __restrict__ src,
                                                   const int* __restrict__ dst,
                                                   int* __restrict__ hist,
                                                   int NBK, int NBLK, int E) {
  __shared__ int hD[MAXBK], hS[MAXBK];
  int t = threadIdx.x, blk = blockIdx.x;
  for (int b = t; b < NBK; b += 256) { hD[b] = 0; hS[b] = 0; }
  __syncthreads();
  int e0 = blk * EPB;
#pragma unroll
  for (int j = 0; j < EPB / 256; ++j) {
    int idx = e0 + j * 256 + t;
    if (idx < E) {
      atomicAdd(&hD[dst[idx] >> 8], 1);
      atomicAdd(&hS[src[idx] >> 8], 1);
    }
  }
  __syncthreads();
  for (int b = t; b < NBK; b += 256) {
    hist[(size_t)b * NBLK + blk] = hD[b];
    hist[(size_t)(NBK + b) * NBLK + blk] = hS[b];
  }
}

// exclusive scan of cnt[0..nbk) into pos[0..nbk), nbk <= 512, 256 threads
__device__ void excl_scan_lds(int* cnt, int* pos, int t, int nbk) {
  for (int b = t; b < nbk; b += 256) pos[b] = cnt[b];
  __syncthreads();
  for (int d = 1; d < 256; d <<= 1) {
    int u = (t < nbk && t >= d) ? pos[t - d] : 0;
    __syncthreads();
    if (t < nbk && t >= d) pos[t] += u;
    __syncthreads();
  }
  int m2 = nbk - 256;
  int s0 = (m2 > 0) ? pos[255] : 0;
  for (int d = 1; d < 256; d <<= 1) {
    int u = (m2 > 0 && t < m2 && t >= d) ? pos[256 + t - d] : 0;
    __syncthreads();
    if (m2 > 0 && t < m2 && t >= d) pos[256 + t] += u;
    __syncthreads();
  }
  if (m2 > 0 && t < m2) pos[256 + t] += s0;
  __syncthreads();
  for (int b = t; b < nbk; b += 256) pos[b] -= cnt[b];
  __syncthreads();
}

// G3: LDS-staged scatter. pairs_d: (src,dst) sorted by dst-bucket; srcs_s: src sorted by src-bucket.
__global__ __launch_bounds__(256) void scatter_kernel(const int* __restrict__ src,
                                                      const int* __restrict__ dst,
                                                      const int* __restrict__ P,
                                                      int2* __restrict__ pairs_d,
                                                      int* __restrict__ srcs_s,
                                                      int NBK, int NBLK, int E) {
  __shared__ int cnt[MAXBK], pos[MAXBK], cur[MAXBK], gb[MAXBK];
  __shared__ int2 stage[EPB];
  int t = threadIdx.x, blk = blockIdx.x;
  int e0 = blk * EPB;
  int ne = E - e0; if (ne > EPB) ne = EPB;

  // ---- D phase ----
  for (int b = t; b < NBK; b += 256) cnt[b] = 0;
  __syncthreads();
#pragma unroll
  for (int j = 0; j < EPB / 256; ++j) {
    int idx = e0 + j * 256 + t;
    if (idx < E) atomicAdd(&cnt[dst[idx] >> 8], 1);
  }
  __syncthreads();
  excl_scan_lds(cnt, pos, t, NBK);
  for (int b = t; b < NBK; b += 256) { cur[b] = pos[b]; gb[b] = P[(size_t)b * NBLK + blk]; }
  __syncthreads();
#pragma unroll
  for (int j = 0; j < EPB / 256; ++j) {
    int idx = e0 + j * 256 + t;
    if (idx < E) {
      int d = dst[idx];
      int r = atomicAdd(&cur[d >> 8], 1);
      stage[r] = make_int2(src[idx], d);
    }
  }
  __syncthreads();
  for (int i = t; i < ne; i += 256) {
    int2 p = stage[i];
    int b = p.y >> 8;
    pairs_d[gb[b] + (i - pos[b])] = p;
  }
  __syncthreads();

  // ---- S phase (reuse stage as int[]) ----
  int* stage_i = (int*)stage;
  for (int b = t; b < NBK; b += 256) cnt[b] = 0;
  __syncthreads();
#pragma unroll
  for (int j = 0; j < EPB / 256; ++j) {
    int idx = e0 + j * 256 + t;
    if (idx < E) atomicAdd(&cnt[src[idx] >> 8], 1);
  }
  __syncthreads();
  excl_scan_lds(cnt, pos, t, NBK);
  for (int b = t; b < NBK; b += 256) {
    cur[b] = pos[b];
    gb[b] = P[(size_t)(NBK + b) * NBLK + blk] - E;
  }
  __syncthreads();
#pragma unroll
  for (int j = 0; j < EPB / 256; ++j) {
    int idx = e0 + j * 256 + t;
    if (idx < E) {
      int s = src[idx];
      int r = atomicAdd(&cur[s >> 8], 1);
      stage_i[r] = s;
    }
  }
  __syncthreads();
  for (int i = t; i < ne; i += 256) {
    int s = stage_i[i];
    int b = s >> 8;
    srcs_s[gb[b] + (i - pos[b])] = s;
  }
}

// G4: per-bucket CSR build + in-degree norm. One block per dst-bucket (256 nodes).
__global__ __launch_bounds__(256) void csr_bucket(const int2* __restrict__ pairs_d,
                                                  const int* __restrict__ P,
                                                  int* __restrict__ row_off,
                                                  float* __restrict__ norm_d,
                                                  int* __restrict__ csr,
                                                  int NBK, int NBLK, int N, int E) {
  __shared__ int cnt[256], pos[256], cur[256];
  int b = blockIdx.x, t = threadIdx.x;
  int bstart = P[(size_t)b * NBLK];
  int bend = (b + 1 < NBK) ? P[(size_t)(b + 1) * NBLK] : E;
  cnt[t] = 0;
  __syncthreads();
  for (int i = bstart + t; i < bend; i += 256) atomicAdd(&cnt[pairs_d[i].y & 255], 1);
  __syncthreads();
  pos[t] = cnt[t];
  __syncthreads();
  for (int d = 1; d < 256; d <<= 1) {
    int u = (t >= d) ? pos[t - d] : 0;
    __syncthreads();
    if (t >= d) pos[t] += u;
    __syncthreads();
  }
  int excl = pos[t] - cnt[t];
  int node = b * 256 + t;
  if (node < N) {
    row_off[node] = bstart + excl;
    norm_d[node] = cnt[t] > 0 ? rsqrtf((float)cnt[t]) : 0.f;
  }
  if (b == NBK - 1 && t == 255) row_off[N] = E;
  cur[t] = excl;
  __syncthreads();
  for (int i = bstart + t; i < bend; i += 256) {
    int2 p = pairs_d[i];
    int r = atomicAdd(&cur[p.y & 255], 1);
    csr[bstart + r] = p.x;
  }
}

// G5: per-bucket out-degree norm.
__global__ __launch_bounds__(256) void outdeg_bucket(const int* __restrict__ srcs_s,
                                                     const int* __restrict__ P,
                                                     float* __restrict__ norm_s,
                                                     int NBK, int NBLK, int N, int E) {
  __shared__ int cnt[256];
  int b = blockIdx.x, t = threadIdx.x;
  size_t SOFF = (size_t)NBK * NBLK;
  int sstart = P[SOFF + (size_t)b * NBLK] - E;
  int send = (b + 1 < NBK) ? P[SOFF + (size_t)(b + 1) * NBLK] - E : E;
  cnt[t] = 0;
  __syncthreads();
  for (int i = sstart + t; i < send; i += 256) atomicAdd(&cnt[srcs_s[i] & 255], 1);
  __syncthreads();
  int node = b * 256 + t;
  if (node < N) norm_s[node] = cnt[t] > 0 ? rsqrtf((float)cnt[t]) : 0.f;
}

// ---------------- generic 3-kernel decoupled scan ----------------
__global__ void scan_part(const int* __restrict__ arr, int* __restrict__ bsum, int len) {
  int base = blockIdx.x * SCAN_CHUNK + threadIdx.x * 8;
  int s = 0;
#pragma unroll
  for (int j = 0; j < 8; ++j) {
    int i = base + j;
    if (i < len) s += arr[i];
  }
#pragma unroll
  for (int d = 1; d < 64; d <<= 1) s += __shfl_xor(s, d);
  __shared__ int ws[4];
  int lane = threadIdx.x & 63, w = threadIdx.x >> 6;
  if (lane == 0) ws[w] = s;
  __syncthreads();
  if (threadIdx.x == 0) bsum[blockIdx.x] = ws[0] + ws[1] + ws[2] + ws[3];
}

__global__ __launch_bounds__(1024) void scan_bsum(int* __restrict__ bsum, int nb) {
  __shared__ int sm[1024];
  int t = threadIdx.x;
  sm[t] = (t < nb) ? bsum[t] : 0;
  __syncthreads();
  for (int d = 1; d < 1024; d <<= 1) {
    int v = (t >= d) ? sm[t - d] : 0;
    __syncthreads();
    sm[t] += v;
    __syncthreads();
  }
  if (t < nb) bsum[t] = (t == 0) ? 0 : sm[t - 1];   // exclusive
}

__global__ void scan_final(const int* __restrict__ arr, const int* __restrict__ bsum_ex,
                           int* __restrict__ outp, int len, int total) {
  int base = blockIdx.x * SCAN_CHUNK + threadIdx.x * 8;
  int v[8], pre[8];
  int s = 0;
#pragma unroll
  for (int j = 0; j < 8; ++j) {
    int i = base + j;
    v[j] = (i < len) ? arr[i] : 0;
    pre[j] = s;
    s += v[j];
  }
  int lane = threadIdx.x & 63, w = threadIdx.x >> 6;
  int inc = s;
#pragma unroll
  for (int d = 1; d < 64; d <<= 1) {
    int u = __shfl_up(inc, d);
    if (lane >= d) inc += u;
  }
  __shared__ int wsum[4], woff[4];
  if (lane == 63) wsum[w] = inc;
  __syncthreads();
  if (threadIdx.x == 0) {
    int r = 0;
    for (int q = 0; q < 4; ++q) { woff[q] = r; r += wsum[q]; }
  }
  __syncthreads();
  int ex = (inc - s) + woff[w] + bsum_ex[blockIdx.x];
#pragma unroll
  for (int j = 0; j < 8; ++j) {
    int i = base + j;
    if (i < len) outp[i] = ex + pre[j];
  }
  if (blockIdx.x == 0 && threadIdx.x == 0) outp[len] = total;
}

// ---------------- bf16 MFMA GEMM with per-row output scale, bf16 output ----------------
template<int BM, int BN, int KTOT, int WM, int WN>
__global__ __launch_bounds__(256) void mfma_gemm_scale(
    const ushort* __restrict__ A, const ushort* __restrict__ BT,
    const float* __restrict__ scale, ushort* __restrict__ C, int M) {
  constexpr int BK = 64;
  constexpr int FM = (BM / WM) / 16;
  constexpr int FN = (BN / WN) / 16;
  constexpr int ABYTES = BM * BK * 2;
  constexpr int BBYTES = BN * BK * 2;
  __shared__ char lds[ABYTES + BBYTES];
  char* Asm = lds;
  char* Bsm = lds + ABYTES;

  const int tid = threadIdx.x;
  const int lane = tid & 63;
  const int w = tid >> 6;
  const int wm = w / WN, wn = w % WN;
  const int m0 = blockIdx.x * BM;

  f32x4 acc[FM][FN];
#pragma unroll
  for (int m = 0; m < FM; ++m)
#pragma unroll
    for (int n = 0; n < FN; ++n) acc[m][n] = (f32x4){0.f, 0.f, 0.f, 0.f};

  const int ra = lane & 15;
  const int kg = lane >> 4;

  for (int kt = 0; kt < KTOT / BK; ++kt) {
#pragma unroll
    for (int s = 0; s < ABYTES / 4096; ++s) {
      int L = s * 4096 + tid * 16;
      int r = L >> 7;
      int slot = (L >> 4) & 7;
      int gr = m0 + r; if (gr >= M) gr = M - 1;
      const char* gp = (const char*)A + (size_t)gr * (KTOT * 2) + kt * (BK * 2)
                     + ((slot * 16) ^ ((r & 7) << 4));
      __builtin_amdgcn_global_load_lds(
          (const __attribute__((address_space(1))) unsigned*)gp,
          (__attribute__((address_space(3))) unsigned*)(Asm + L), 16, 0, 0);
    }
#pragma unroll
    for (int s = 0; s < BBYTES / 4096; ++s) {
      int L = s * 4096 + tid * 16;
      int r = L >> 7;
      int slot = (L >> 4) & 7;
      const char* gp = (const char*)BT + (size_t)r * (KTOT * 2) + kt * (BK * 2)
                     + ((slot * 16) ^ ((r & 7) << 4));
      __builtin_amdgcn_global_load_lds(
          (const __attribute__((address_space(1))) unsigned*)gp,
          (__attribute__((address_space(3))) unsigned*)(Bsm + L), 16, 0, 0);
    }
    __syncthreads();

#pragma unroll
    for (int ks = 0; ks < 2; ++ks) {
      bf16x8 af[FM], bfr[FN];
#pragma unroll
      for (int m = 0; m < FM; ++m) {
        int r = wm * (BM / WM) + m * 16 + ra;
        int cb = ks * 64 + kg * 16;
        af[m] = *(const bf16x8*)(Asm + r * 128 + (cb ^ ((r & 7) << 4)));
      }
#pragma unroll
      for (int n = 0; n < FN; ++n) {
        int c = wn * (BN / WN) + n * 16 + ra;
        int cb = ks * 64 + kg * 16;
        bfr[n] = *(const bf16x8*)(Bsm + c * 128 + (cb ^ ((c & 7) << 4)));
      }
#pragma unroll
      for (int m = 0; m < FM; ++m)
#pragma unroll
        for (int n = 0; n < FN; ++n)
          acc[m][n] = __builtin_amdgcn_mfma_f32_16x16x32_bf16(af[m], bfr[n], acc[m][n], 0, 0, 0);
    }
    __syncthreads();
  }

#pragma unroll
  for (int m = 0; m < FM; ++m) {
#pragma unroll
    for (int j = 0; j < 4; ++j) {
      int rl = wm * (BM / WM) + m * 16 + (lane >> 4) * 4 + j;
      int gr = m0 + rl;
      if (gr < M) {
        float sc = scale[gr];
#pragma unroll
        for (int n = 0; n < FN; ++n) {
          int c = wn * (BN / WN) + n * 16 + (lane & 15);
          C[(size_t)gr * BN + c] = f2bf(acc[m][n][j] * sc);
        }
      }
    }
  }
}

// ---------------- gathers ----------------
__global__ void gather1(const ushort* __restrict__ h1, const int* __restrict__ off,
                        const int* __restrict__ csr, const float* __restrict__ nd,
                        const float* __restrict__ b1, ushort* __restrict__ x2, int N) {
  int w = (blockIdx.x * blockDim.x + threadIdx.x) >> 6;
  int lane = threadIdx.x & 63;
  if (w >= N) return;
  int lo = off[w], hi = off[w + 1];
  const unsigned* h = (const unsigned*)h1;
  float sx = 0.f, sy = 0.f;
#define ACC1(u) { sx += __builtin_bit_cast(float, (u) << 16); \
                  sy += __builtin_bit_cast(float, (u) & 0xFFFF0000u); }
  int j = lo;
  for (; j + 8 <= hi; j += 8) {
    int s0 = csr[j+0], s1 = csr[j+1], s2 = csr[j+2], s3 = csr[j+3];
    int s4 = csr[j+4], s5 = csr[j+5], s6 = csr[j+6], s7 = csr[j+7];
    unsigned u0 = h[(size_t)s0 * 64 + lane];
    unsigned u1 = h[(size_t)s1 * 64 + lane];
    unsigned u2 = h[(size_t)s2 * 64 + lane];
    unsigned u3 = h[(size_t)s3 * 64 + lane];
    unsigned u4 = h[(size_t)s4 * 64 + lane];
    unsigned u5 = h[(size_t)s5 * 64 + lane];
    unsigned u6 = h[(size_t)s6 * 64 + lane];
    unsigned u7 = h[(size_t)s7 * 64 + lane];
    ACC1(u0) ACC1(u1) ACC1(u2) ACC1(u3) ACC1(u4) ACC1(u5) ACC1(u6) ACC1(u7)
  }
  for (; j + 4 <= hi; j += 4) {
    int s0 = csr[j+0], s1 = csr[j+1], s2 = csr[j+2], s3 = csr[j+3];
    unsigned u0 = h[(size_t)s0 * 64 + lane];
    unsigned u1 = h[(size_t)s1 * 64 + lane];
    unsigned u2 = h[(size_t)s2 * 64 + lane];
    unsigned u3 = h[(size_t)s3 * 64 + lane];
    ACC1(u0) ACC1(u1) ACC1(u2) ACC1(u3)
  }
  for (; j < hi; ++j) {
    int s = csr[j];
    unsigned u = h[(size_t)s * 64 + lane];
    ACC1(u)
  }
#undef ACC1
  float sc = nd[w];
  float2 bb = ((const float2*)b1)[lane];
  float ox = fmaxf(sx * sc + bb.x, 0.f);
  float oy = fmaxf(sy * sc + bb.y, 0.f);
  ushort2 o; o.x = f2bf(ox); o.y = f2bf(oy);
  ((ushort2*)x2)[(size_t)w * 64 + lane] = o;
}

__global__ void gather2(const ushort* __restrict__ h2, const int* __restrict__ off,
                        const int* __restrict__ csr, const float* __restrict__ nd,
                        const float* __restrict__ b2, float* __restrict__ out, int N) {
  int wv = (blockIdx.x * blockDim.x + threadIdx.x) >> 6;
  int lane = threadIdx.x & 63;
  int grp = lane >> 5;
  int sub = lane & 31;
  int node = wv * 2 + grp;
  if (node >= N) return;
  int lo = off[node], hi = off[node + 1];
  const unsigned* h = (const unsigned*)h2;
  float s0 = 0.f, s1 = 0.f;
#define ACC2(u) { s0 += __builtin_bit_cast(float, (u) << 16); \
                  s1 += __builtin_bit_cast(float, (u) & 0xFFFF0000u); }
  int j = lo;
  for (; j + 8 <= hi; j += 8) {
    int i0 = csr[j+0], i1 = csr[j+1], i2 = csr[j+2], i3 = csr[j+3];
    int i4 = csr[j+4], i5 = csr[j+5], i6 = csr[j+6], i7 = csr[j+7];
    unsigned u0 = h[(size_t)i0 * 32 + sub];
    unsigned u1 = h[(size_t)i1 * 32 + sub];
    unsigned u2 = h[(size_t)i2 * 32 + sub];
    unsigned u3 = h[(size_t)i3 * 32 + sub];
    unsigned u4 = h[(size_t)i4 * 32 + sub];
    unsigned u5 = h[(size_t)i5 * 32 + sub];
    unsigned u6 = h[(size_t)i6 * 32 + sub];
    unsigned u7 = h[(size_t)i7 * 32 + sub];
    ACC2(u0) ACC2(u1) ACC2(u2) ACC2(u3) ACC2(u4) ACC2(u5) ACC2(u6) ACC2(u7)
  }
  for (; j + 4 <= hi; j += 4) {
    int i0 = csr[j+0], i1 = csr[j+1], i2 = csr[j+2], i3 = csr[j+3];
    unsigned u0 = h[(size_t)i0 * 32 + sub];
    unsigned u1 = h[(size_t)i1 * 32 + sub];
    unsigned u2 = h[(size_t)i2 * 32 + sub];
    unsigned u3 = h[(size_t)i3 * 32 + sub];
    ACC2(u0) ACC2(u1) ACC2(u2) ACC2(u3)
  }
  for (; j < hi; ++j) {
    int i0 = csr[j];
    unsigned u = h[(size_t)i0 * 32 + sub];
    ACC2(u)
  }
#undef ACC2
  float scn = nd[node];
  float2 bb = ((const float2*)b2)[sub];
  float v0 = s0 * scn + bb.x;
  float v1 = s1 * scn + bb.y;
  float2 o;
  o.x = 1.f / (1.f + expf(-v0));
  o.y = 1.f / (1.f + expf(-v1));
  ((float2*)out)[(size_t)node * 32 + sub] = o;
}

extern "C" void kernel_launch(void* const* d_in, const int* in_sizes, int n_in,
                              void* d_out, int out_size, void* d_ws, size_t ws_size,
                              hipStream_t stream) {
  const float* feat = (const float*)d_in[0];
  const int*   src  = (const int*)d_in[1];
  const int*   dst  = (const int*)d_in[2];
  const float* W1   = (const float*)d_in[3];
  const float* b1   = (const float*)d_in[4];
  const float* W2   = (const float*)d_in[5];
  const float* b2   = (const float*)d_in[6];
  float* out = (float*)d_out;

  const int N = in_sizes[0] / IN_F;   // 100000
  const int E = in_sizes[1];          // 1600000

  const int NBK  = (N + 255) >> 8;            // 391 coarse buckets
  const int NBLK = (E + EPB - 1) / EPB;       // 391 sort blocks
  const int HLEN = 2 * NBK * NBLK;            // hist length

  size_t off = 0;
  auto alloc = [&](size_t bytes) -> void* {
    void* p = (char*)d_ws + off;
    off = (off + bytes + 255) & ~(size_t)255;
    return p;
  };
  int*    hist    = (int*)alloc((size_t)HLEN * 4);
  int*    P       = (int*)alloc((size_t)(HLEN + 1) * 4);
  int*    bsum    = (int*)alloc((size_t)1024 * 4);
  int2*   pairs_d = (int2*)alloc((size_t)E * 8);
  int*    srcs_s  = (int*)alloc((size_t)E * 4);
  float*  norm_s  = (float*)alloc((size_t)N * 4);
  float*  norm_d  = (float*)alloc((size_t)N * 4);
  int*    row_off = (int*)alloc((size_t)(N + 1) * 4);
  int*    csr     = (int*)alloc((size_t)E * 4);
  ushort* featbf  = (ushort*)alloc((size_t)N * IN_F * 2);
  ushort* w1t     = (ushort*)alloc((size_t)H_F * IN_F * 2);
  ushort* w2t     = (ushort*)alloc((size_t)N_CLS * H_F * 2);
  ushort* h1      = (ushort*)alloc((size_t)N * H_F * 2);
  ushort* x2bf    = (ushort*)alloc((size_t)N * H_F * 2);
  ushort* h2      = (ushort*)alloc((size_t)N * N_CLS * 2);
  (void)ws_size;

  conv_feat<<<2048, 256, 0, stream>>>(feat, featbf, N * IN_F / 4);
  conv_wT<<<(IN_F * H_F + 255) / 256, 256, 0, stream>>>(W1, w1t, IN_F, H_F);
  conv_wT<<<(H_F * N_CLS + 255) / 256, 256, 0, stream>>>(W2, w2t, H_F, N_CLS);

  // graph build (atomic-free)
  hist_kernel<<<NBLK, 256, 0, stream>>>(src, dst, hist, NBK, NBLK, E);
  const int NBS = (HLEN + SCAN_CHUNK - 1) / SCAN_CHUNK;
  scan_part<<<NBS, 256, 0, stream>>>(hist, bsum, HLEN);
  scan_bsum<<<1, 1024, 0, stream>>>(bsum, NBS);
  scan_final<<<NBS, 256, 0, stream>>>(hist, bsum, P, HLEN, 2 * E);
  scatter_kernel<<<NBLK, 256, 0, stream>>>(src, dst, P, pairs_d, srcs_s, NBK, NBLK, E);
  csr_bucket<<<NBK, 256, 0, stream>>>(pairs_d, P, row_off, norm_d, csr, NBK, NBLK, N, E);
  outdeg_bucket<<<NBK, 256, 0, stream>>>(srcs_s, P, norm_s, NBK, NBLK, N, E);

  // layer 1
  mfma_gemm_scale<128, 128, 256, 2, 2><<<(N + 127) / 128, 256, 0, stream>>>(
      featbf, w1t, norm_s, h1, N);
  gather1<<<(N * 64 + 255) / 256, 256, 0, stream>>>(h1, row_off, csr, norm_d, b1, x2bf, N);

  // layer 2
  mfma_gemm_scale<128, 64, 128, 2, 2><<<(N + 127) / 128, 256, 0, stream>>>(
      x2bf, w2t, norm_s, h2, N);
  int pairs = (N + 1) / 2;
  gather2<<<(pairs * 64 + 255) / 256, 256, 0, stream>>>(h2, row_off, csr, norm_d, b2, out, N);
}

// Round 8
// 229.123 us; speedup vs baseline: 4.8124x; 1.0468x over previous
//
#include <hip/hip_runtime.h>
#include <cmath>

#define IN_F 256
#define H_F  128
#define N_CLS 64
#define SCAN_CHUNK 2048   // 256 threads * 8 elems
#define EPB 4096          // edges per block in sort kernels
#define MAXBK 400         // max coarse buckets (ceil(100096/256)=391)

typedef __attribute__((ext_vector_type(8))) short bf16x8;
typedef __attribute__((ext_vector_type(4))) float f32x4;

__device__ __forceinline__ ushort f2bf(float x) {
  unsigned b = __builtin_bit_cast(unsigned, x);
  b += 0x7FFF + ((b >> 16) & 1);          // RNE
  return (ushort)(b >> 16);
}

// ---------------- tiny weight transpose->bf16 ----------------
__global__ void conv_wT(const float* __restrict__ W, ushort* __restrict__ WT, int K, int N) {
  int i = blockIdx.x * blockDim.x + threadIdx.x;
  if (i >= K * N) return;
  int k = i / N, n = i % N;
  WT[n * K + k] = f2bf(W[i]);
}

// ---------------- graph build: atomic-free two-level counting sort ----------------
__global__ __launch_bounds__(256) void hist_kernel(const int* __restrict__ src,
                                                   const int* __restrict__ dst,
                                                   int* __restrict__ hist,
                                                   int NBK, int NBLK, int E) {
  __shared__ int hD[MAXBK], hS[MAXBK];
  int t = threadIdx.x, blk = blockIdx.x;
  for (int b = t; b < NBK; b += 256) { hD[b] = 0; hS[b] = 0; }
  __syncthreads();
  int e0 = blk * EPB;
#pragma unroll
  for (int j = 0; j < EPB / 256; ++j) {
    int idx = e0 + j * 256 + t;
    if (idx < E) {
      atomicAdd(&hD[dst[idx] >> 8], 1);
      atomicAdd(&hS[src[idx] >> 8], 1);
    }
  }
  __syncthreads();
  for (int b = t; b < NBK; b += 256) {
    hist[(size_t)b * NBLK + blk] = hD[b];
    hist[(size_t)(NBK + b) * NBLK + blk] = hS[b];
  }
}

// exclusive scan of cnt[0..nbk) into pos[0..nbk), nbk <= 512, 256 threads
__device__ void excl_scan_lds(int* cnt, int* pos, int t, int nbk) {
  for (int b = t; b < nbk; b += 256) pos[b] = cnt[b];
  __syncthreads();
  for (int d = 1; d < 256; d <<= 1) {
    int u = (t < nbk && t >= d) ? pos[t - d] : 0;
    __syncthreads();
    if (t < nbk && t >= d) pos[t] += u;
    __syncthreads();
  }
  int m2 = nbk - 256;
  int s0 = (m2 > 0) ? pos[255] : 0;
  for (int d = 1; d < 256; d <<= 1) {
    int u = (m2 > 0 && t < m2 && t >= d) ? pos[256 + t - d] : 0;
    __syncthreads();
    if (m2 > 0 && t < m2 && t >= d) pos[256 + t] += u;
    __syncthreads();
  }
  if (m2 > 0 && t < m2) pos[256 + t] += s0;
  __syncthreads();
  for (int b = t; b < nbk; b += 256) pos[b] -= cnt[b];
  __syncthreads();
}

__global__ __launch_bounds__(256) void scatter_kernel(const int* __restrict__ src,
                                                      const int* __restrict__ dst,
                                                      const int* __restrict__ P,
                                                      int2* __restrict__ pairs_d,
                                                      int* __restrict__ srcs_s,
                                                      int NBK, int NBLK, int E) {
  __shared__ int cnt[MAXBK], pos[MAXBK], cur[MAXBK], gb[MAXBK];
  __shared__ int2 stage[EPB];
  int t = threadIdx.x, blk = blockIdx.x;
  int e0 = blk * EPB;
  int ne = E - e0; if (ne > EPB) ne = EPB;

  // ---- D phase ----
  for (int b = t; b < NBK; b += 256) cnt[b] = 0;
  __syncthreads();
#pragma unroll
  for (int j = 0; j < EPB / 256; ++j) {
    int idx = e0 + j * 256 + t;
    if (idx < E) atomicAdd(&cnt[dst[idx] >> 8], 1);
  }
  __syncthreads();
  excl_scan_lds(cnt, pos, t, NBK);
  for (int b = t; b < NBK; b += 256) { cur[b] = pos[b]; gb[b] = P[(size_t)b * NBLK + blk]; }
  __syncthreads();
#pragma unroll
  for (int j = 0; j < EPB / 256; ++j) {
    int idx = e0 + j * 256 + t;
    if (idx < E) {
      int d = dst[idx];
      int r = atomicAdd(&cur[d >> 8], 1);
      stage[r] = make_int2(src[idx], d);
    }
  }
  __syncthreads();
  for (int i = t; i < ne; i += 256) {
    int2 p = stage[i];
    int b = p.y >> 8;
    pairs_d[gb[b] + (i - pos[b])] = p;
  }
  __syncthreads();

  // ---- S phase (reuse stage as int[]) ----
  int* stage_i = (int*)stage;
  for (int b = t; b < NBK; b += 256) cnt[b] = 0;
  __syncthreads();
#pragma unroll
  for (int j = 0; j < EPB / 256; ++j) {
    int idx = e0 + j * 256 + t;
    if (idx < E) atomicAdd(&cnt[src[idx] >> 8], 1);
  }
  __syncthreads();
  excl_scan_lds(cnt, pos, t, NBK);
  for (int b = t; b < NBK; b += 256) {
    cur[b] = pos[b];
    gb[b] = P[(size_t)(NBK + b) * NBLK + blk] - E;
  }
  __syncthreads();
#pragma unroll
  for (int j = 0; j < EPB / 256; ++j) {
    int idx = e0 + j * 256 + t;
    if (idx < E) {
      int s = src[idx];
      int r = atomicAdd(&cur[s >> 8], 1);
      stage_i[r] = s;
    }
  }
  __syncthreads();
  for (int i = t; i < ne; i += 256) {
    int s = stage_i[i];
    int b = s >> 8;
    srcs_s[gb[b] + (i - pos[b])] = s;
  }
}

__global__ __launch_bounds__(256) void csr_bucket(const int2* __restrict__ pairs_d,
                                                  const int* __restrict__ P,
                                                  int* __restrict__ row_off,
                                                  float* __restrict__ norm_d,
                                                  int* __restrict__ csr,
                                                  int NBK, int NBLK, int N, int E) {
  __shared__ int cnt[256], pos[256], cur[256];
  int b = blockIdx.x, t = threadIdx.x;
  int bstart = P[(size_t)b * NBLK];
  int bend = (b + 1 < NBK) ? P[(size_t)(b + 1) * NBLK] : E;
  cnt[t] = 0;
  __syncthreads();
  for (int i = bstart + t; i < bend; i += 256) atomicAdd(&cnt[pairs_d[i].y & 255], 1);
  __syncthreads();
  pos[t] = cnt[t];
  __syncthreads();
  for (int d = 1; d < 256; d <<= 1) {
    int u = (t >= d) ? pos[t - d] : 0;
    __syncthreads();
    if (t >= d) pos[t] += u;
    __syncthreads();
  }
  int excl = pos[t] - cnt[t];
  int node = b * 256 + t;
  if (node < N) {
    row_off[node] = bstart + excl;
    norm_d[node] = cnt[t] > 0 ? rsqrtf((float)cnt[t]) : 0.f;
  }
  if (b == NBK - 1 && t == 255) row_off[N] = E;
  cur[t] = excl;
  __syncthreads();
  for (int i = bstart + t; i < bend; i += 256) {
    int2 p = pairs_d[i];
    int r = atomicAdd(&cur[p.y & 255], 1);
    csr[bstart + r] = p.x;
  }
}

__global__ __launch_bounds__(256) void outdeg_bucket(const int* __restrict__ srcs_s,
                                                     const int* __restrict__ P,
                                                     float* __restrict__ norm_s,
                                                     int NBK, int NBLK, int N, int E) {
  __shared__ int cnt[256];
  int b = blockIdx.x, t = threadIdx.x;
  size_t SOFF = (size_t)NBK * NBLK;
  int sstart = P[SOFF + (size_t)b * NBLK] - E;
  int send = (b + 1 < NBK) ? P[SOFF + (size_t)(b + 1) * NBLK] - E : E;
  cnt[t] = 0;
  __syncthreads();
  for (int i = sstart + t; i < send; i += 256) atomicAdd(&cnt[srcs_s[i] & 255], 1);
  __syncthreads();
  int node = b * 256 + t;
  if (node < N) norm_s[node] = cnt[t] > 0 ? rsqrtf((float)cnt[t]) : 0.f;
}

// ---------------- generic 3-kernel decoupled scan ----------------
__global__ void scan_part(const int* __restrict__ arr, int* __restrict__ bsum, int len) {
  int base = blockIdx.x * SCAN_CHUNK + threadIdx.x * 8;
  int s = 0;
#pragma unroll
  for (int j = 0; j < 8; ++j) {
    int i = base + j;
    if (i < len) s += arr[i];
  }
#pragma unroll
  for (int d = 1; d < 64; d <<= 1) s += __shfl_xor(s, d);
  __shared__ int ws[4];
  int lane = threadIdx.x & 63, w = threadIdx.x >> 6;
  if (lane == 0) ws[w] = s;
  __syncthreads();
  if (threadIdx.x == 0) bsum[blockIdx.x] = ws[0] + ws[1] + ws[2] + ws[3];
}

__global__ __launch_bounds__(1024) void scan_bsum(int* __restrict__ bsum, int nb) {
  __shared__ int sm[1024];
  int t = threadIdx.x;
  sm[t] = (t < nb) ? bsum[t] : 0;
  __syncthreads();
  for (int d = 1; d < 1024; d <<= 1) {
    int v = (t >= d) ? sm[t - d] : 0;
    __syncthreads();
    sm[t] += v;
    __syncthreads();
  }
  if (t < nb) bsum[t] = (t == 0) ? 0 : sm[t - 1];   // exclusive
}

__global__ void scan_final(const int* __restrict__ arr, const int* __restrict__ bsum_ex,
                           int* __restrict__ outp, int len, int total) {
  int base = blockIdx.x * SCAN_CHUNK + threadIdx.x * 8;
  int v[8], pre[8];
  int s = 0;
#pragma unroll
  for (int j = 0; j < 8; ++j) {
    int i = base + j;
    v[j] = (i < len) ? arr[i] : 0;
    pre[j] = s;
    s += v[j];
  }
  int lane = threadIdx.x & 63, w = threadIdx.x >> 6;
  int inc = s;
#pragma unroll
  for (int d = 1; d < 64; d <<= 1) {
    int u = __shfl_up(inc, d);
    if (lane >= d) inc += u;
  }
  __shared__ int wsum[4], woff[4];
  if (lane == 63) wsum[w] = inc;
  __syncthreads();
  if (threadIdx.x == 0) {
    int r = 0;
    for (int q = 0; q < 4; ++q) { woff[q] = r; r += wsum[q]; }
  }
  __syncthreads();
  int ex = (inc - s) + woff[w] + bsum_ex[blockIdx.x];
#pragma unroll
  for (int j = 0; j < 8; ++j) {
    int i = base + j;
    if (i < len) outp[i] = ex + pre[j];
  }
  if (blockIdx.x == 0 && threadIdx.x == 0) outp[len] = total;
}

// ---------------- layer-1 GEMM: f32 A fused-convert, bf16 MFMA, scale, bf16 out ----
// h1[m,0:128] = bf16((feat[m,0:256] @ W1) * ns[m]); A reg-staged f32->bf16 with
// XOR swizzle applied on ds_write AND ds_read (both-sides). B via global_load_lds.
__global__ __launch_bounds__(256) void mfma_gemm1(
    const float* __restrict__ A, const ushort* __restrict__ BT,
    const float* __restrict__ scale, ushort* __restrict__ C, int M) {
  constexpr int BM = 128, BN = 128, KTOT = 256, BK = 64, WM = 2, WN = 2;
  constexpr int FM = (BM / WM) / 16;   // 4
  constexpr int FN = (BN / WN) / 16;   // 4
  constexpr int ABYTES = BM * BK * 2;  // 16 KB
  constexpr int BBYTES = BN * BK * 2;  // 16 KB
  __shared__ char lds[ABYTES + BBYTES];
  char* Asm = lds;
  char* Bsm = lds + ABYTES;

  const int tid = threadIdx.x;
  const int lane = tid & 63;
  const int w = tid >> 6;
  const int wm = w / WN, wn = w % WN;
  const int m0 = blockIdx.x * BM;

  f32x4 acc[FM][FN];
#pragma unroll
  for (int m = 0; m < FM; ++m)
#pragma unroll
    for (int n = 0; n < FN; ++n) acc[m][n] = (f32x4){0.f, 0.f, 0.f, 0.f};

  const int ra = lane & 15;
  const int kg = lane >> 4;

  for (int kt = 0; kt < KTOT / BK; ++kt) {
    // ---- stage A: f32 global -> regs -> bf16 -> swizzled ds_write ----
#pragma unroll
    for (int s = 0; s < ABYTES / 4096; ++s) {
      int L = s * 4096 + tid * 16;
      int r = L >> 7;            // row 0..127
      int slot = (L >> 4) & 7;   // 16B slot in row
      int gr = m0 + r; if (gr >= M) gr = M - 1;
      const float4* gp = (const float4*)(A + (size_t)gr * KTOT + kt * BK + slot * 8);
      float4 va = gp[0], vb = gp[1];
      bf16x8 o;
      o[0] = (short)f2bf(va.x); o[1] = (short)f2bf(va.y);
      o[2] = (short)f2bf(va.z); o[3] = (short)f2bf(va.w);
      o[4] = (short)f2bf(vb.x); o[5] = (short)f2bf(vb.y);
      o[6] = (short)f2bf(vb.z); o[7] = (short)f2bf(vb.w);
      *(bf16x8*)(Asm + (L ^ ((r & 7) << 4))) = o;
    }
    // ---- stage B tile [BN][BK] via global_load_lds (pre-swizzled source) ----
#pragma unroll
    for (int s = 0; s < BBYTES / 4096; ++s) {
      int L = s * 4096 + tid * 16;
      int r = L >> 7;
      int slot = (L >> 4) & 7;
      const char* gp = (const char*)BT + (size_t)r * (KTOT * 2) + kt * (BK * 2)
                     + ((slot * 16) ^ ((r & 7) << 4));
      __builtin_amdgcn_global_load_lds(
          (const __attribute__((address_space(1))) unsigned*)gp,
          (__attribute__((address_space(3))) unsigned*)(Bsm + L), 16, 0, 0);
    }
    __syncthreads();

#pragma unroll
    for (int ks = 0; ks < 2; ++ks) {
      bf16x8 af[FM], bfr[FN];
#pragma unroll
      for (int m = 0; m < FM; ++m) {
        int r = wm * (BM / WM) + m * 16 + ra;
        int cb = ks * 64 + kg * 16;
        af[m] = *(const bf16x8*)(Asm + r * 128 + (cb ^ ((r & 7) << 4)));
      }
#pragma unroll
      for (int n = 0; n < FN; ++n) {
        int c = wn * (BN / WN) + n * 16 + ra;
        int cb = ks * 64 + kg * 16;
        bfr[n] = *(const bf16x8*)(Bsm + c * 128 + (cb ^ ((c & 7) << 4)));
      }
#pragma unroll
      for (int m = 0; m < FM; ++m)
#pragma unroll
        for (int n = 0; n < FN; ++n)
          acc[m][n] = __builtin_amdgcn_mfma_f32_16x16x32_bf16(af[m], bfr[n], acc[m][n], 0, 0, 0);
    }
    __syncthreads();
  }

#pragma unroll
  for (int m = 0; m < FM; ++m) {
#pragma unroll
    for (int j = 0; j < 4; ++j) {
      int rl = wm * (BM / WM) + m * 16 + (lane >> 4) * 4 + j;
      int gr = m0 + rl;
      if (gr < M) {
        float sc = scale[gr];
#pragma unroll
        for (int n = 0; n < FN; ++n) {
          int c = wn * (BN / WN) + n * 16 + (lane & 15);
          C[(size_t)gr * BN + c] = f2bf(acc[m][n][j] * sc);
        }
      }
    }
  }
}

// ---------------- layer-2 GEMM (bf16 A via global_load_lds) ----------------
template<int BM, int BN, int KTOT, int WM, int WN>
__global__ __launch_bounds__(256) void mfma_gemm_scale(
    const ushort* __restrict__ A, const ushort* __restrict__ BT,
    const float* __restrict__ scale, ushort* __restrict__ C, int M) {
  constexpr int BK = 64;
  constexpr int FM = (BM / WM) / 16;
  constexpr int FN = (BN / WN) / 16;
  constexpr int ABYTES = BM * BK * 2;
  constexpr int BBYTES = BN * BK * 2;
  __shared__ char lds[ABYTES + BBYTES];
  char* Asm = lds;
  char* Bsm = lds + ABYTES;

  const int tid = threadIdx.x;
  const int lane = tid & 63;
  const int w = tid >> 6;
  const int wm = w / WN, wn = w % WN;
  const int m0 = blockIdx.x * BM;

  f32x4 acc[FM][FN];
#pragma unroll
  for (int m = 0; m < FM; ++m)
#pragma unroll
    for (int n = 0; n < FN; ++n) acc[m][n] = (f32x4){0.f, 0.f, 0.f, 0.f};

  const int ra = lane & 15;
  const int kg = lane >> 4;

  for (int kt = 0; kt < KTOT / BK; ++kt) {
#pragma unroll
    for (int s = 0; s < ABYTES / 4096; ++s) {
      int L = s * 4096 + tid * 16;
      int r = L >> 7;
      int slot = (L >> 4) & 7;
      int gr = m0 + r; if (gr >= M) gr = M - 1;
      const char* gp = (const char*)A + (size_t)gr * (KTOT * 2) + kt * (BK * 2)
                     + ((slot * 16) ^ ((r & 7) << 4));
      __builtin_amdgcn_global_load_lds(
          (const __attribute__((address_space(1))) unsigned*)gp,
          (__attribute__((address_space(3))) unsigned*)(Asm + L), 16, 0, 0);
    }
#pragma unroll
    for (int s = 0; s < BBYTES / 4096; ++s) {
      int L = s * 4096 + tid * 16;
      int r = L >> 7;
      int slot = (L >> 4) & 7;
      const char* gp = (const char*)BT + (size_t)r * (KTOT * 2) + kt * (BK * 2)
                     + ((slot * 16) ^ ((r & 7) << 4));
      __builtin_amdgcn_global_load_lds(
          (const __attribute__((address_space(1))) unsigned*)gp,
          (__attribute__((address_space(3))) unsigned*)(Bsm + L), 16, 0, 0);
    }
    __syncthreads();

#pragma unroll
    for (int ks = 0; ks < 2; ++ks) {
      bf16x8 af[FM], bfr[FN];
#pragma unroll
      for (int m = 0; m < FM; ++m) {
        int r = wm * (BM / WM) + m * 16 + ra;
        int cb = ks * 64 + kg * 16;
        af[m] = *(const bf16x8*)(Asm + r * 128 + (cb ^ ((r & 7) << 4)));
      }
#pragma unroll
      for (int n = 0; n < FN; ++n) {
        int c = wn * (BN / WN) + n * 16 + ra;
        int cb = ks * 64 + kg * 16;
        bfr[n] = *(const bf16x8*)(Bsm + c * 128 + (cb ^ ((c & 7) << 4)));
      }
#pragma unroll
      for (int m = 0; m < FM; ++m)
#pragma unroll
        for (int n = 0; n < FN; ++n)
          acc[m][n] = __builtin_amdgcn_mfma_f32_16x16x32_bf16(af[m], bfr[n], acc[m][n], 0, 0, 0);
    }
    __syncthreads();
  }

#pragma unroll
  for (int m = 0; m < FM; ++m) {
#pragma unroll
    for (int j = 0; j < 4; ++j) {
      int rl = wm * (BM / WM) + m * 16 + (lane >> 4) * 4 + j;
      int gr = m0 + rl;
      if (gr < M) {
        float sc = scale[gr];
#pragma unroll
        for (int n = 0; n < FN; ++n) {
          int c = wn * (BN / WN) + n * 16 + (lane & 15);
          C[(size_t)gr * BN + c] = f2bf(acc[m][n][j] * sc);
        }
      }
    }
  }
}

// ---------------- gathers (16-deep MLP unroll) ----------------
__global__ void gather1(const ushort* __restrict__ h1, const int* __restrict__ off,
                        const int* __restrict__ csr, const float* __restrict__ nd,
                        const float* __restrict__ b1, ushort* __restrict__ x2, int N) {
  int w = (blockIdx.x * blockDim.x + threadIdx.x) >> 6;
  int lane = threadIdx.x & 63;
  if (w >= N) return;
  int lo = off[w], hi = off[w + 1];
  const unsigned* h = (const unsigned*)h1;
  float sx = 0.f, sy = 0.f;
#define ACC1(u) { sx += __builtin_bit_cast(float, (u) << 16); \
                  sy += __builtin_bit_cast(float, (u) & 0xFFFF0000u); }
  int j = lo;
  for (; j + 16 <= hi; j += 16) {
    int s0 = csr[j+0], s1 = csr[j+1], s2 = csr[j+2], s3 = csr[j+3];
    int s4 = csr[j+4], s5 = csr[j+5], s6 = csr[j+6], s7 = csr[j+7];
    int s8 = csr[j+8], s9 = csr[j+9], sa = csr[j+10], sb = csr[j+11];
    int sc_ = csr[j+12], sd = csr[j+13], se = csr[j+14], sf = csr[j+15];
    unsigned u0 = h[(size_t)s0 * 64 + lane];
    unsigned u1 = h[(size_t)s1 * 64 + lane];
    unsigned u2 = h[(size_t)s2 * 64 + lane];
    unsigned u3 = h[(size_t)s3 * 64 + lane];
    unsigned u4 = h[(size_t)s4 * 64 + lane];
    unsigned u5 = h[(size_t)s5 * 64 + lane];
    unsigned u6 = h[(size_t)s6 * 64 + lane];
    unsigned u7 = h[(size_t)s7 * 64 + lane];
    unsigned u8 = h[(size_t)s8 * 64 + lane];
    unsigned u9 = h[(size_t)s9 * 64 + lane];
    unsigned ua = h[(size_t)sa * 64 + lane];
    unsigned ub = h[(size_t)sb * 64 + lane];
    unsigned uc = h[(size_t)sc_ * 64 + lane];
    unsigned ud = h[(size_t)sd * 64 + lane];
    unsigned ue = h[(size_t)se * 64 + lane];
    unsigned uf = h[(size_t)sf * 64 + lane];
    ACC1(u0) ACC1(u1) ACC1(u2) ACC1(u3) ACC1(u4) ACC1(u5) ACC1(u6) ACC1(u7)
    ACC1(u8) ACC1(u9) ACC1(ua) ACC1(ub) ACC1(uc) ACC1(ud) ACC1(ue) ACC1(uf)
  }
  for (; j + 4 <= hi; j += 4) {
    int s0 = csr[j+0], s1 = csr[j+1], s2 = csr[j+2], s3 = csr[j+3];
    unsigned u0 = h[(size_t)s0 * 64 + lane];
    unsigned u1 = h[(size_t)s1 * 64 + lane];
    unsigned u2 = h[(size_t)s2 * 64 + lane];
    unsigned u3 = h[(size_t)s3 * 64 + lane];
    ACC1(u0) ACC1(u1) ACC1(u2) ACC1(u3)
  }
  for (; j < hi; ++j) {
    int s = csr[j];
    unsigned u = h[(size_t)s * 64 + lane];
    ACC1(u)
  }
#undef ACC1
  float sc = nd[w];
  float2 bb = ((const float2*)b1)[lane];
  float ox = fmaxf(sx * sc + bb.x, 0.f);
  float oy = fmaxf(sy * sc + bb.y, 0.f);
  ushort2 o; o.x = f2bf(ox); o.y = f2bf(oy);
  ((ushort2*)x2)[(size_t)w * 64 + lane] = o;
}

__global__ void gather2(const ushort* __restrict__ h2, const int* __restrict__ off,
                        const int* __restrict__ csr, const float* __restrict__ nd,
                        const float* __restrict__ b2, float* __restrict__ out, int N) {
  int wv = (blockIdx.x * blockDim.x + threadIdx.x) >> 6;
  int lane = threadIdx.x & 63;
  int grp = lane >> 5;
  int sub = lane & 31;
  int node = wv * 2 + grp;
  if (node >= N) return;
  int lo = off[node], hi = off[node + 1];
  const unsigned* h = (const unsigned*)h2;
  float s0f = 0.f, s1f = 0.f;
#define ACC2(u) { s0f += __builtin_bit_cast(float, (u) << 16); \
                  s1f += __builtin_bit_cast(float, (u) & 0xFFFF0000u); }
  int j = lo;
  for (; j + 16 <= hi; j += 16) {
    int i0 = csr[j+0], i1 = csr[j+1], i2 = csr[j+2], i3 = csr[j+3];
    int i4 = csr[j+4], i5 = csr[j+5], i6 = csr[j+6], i7 = csr[j+7];
    int i8 = csr[j+8], i9 = csr[j+9], ia = csr[j+10], ib = csr[j+11];
    int ic = csr[j+12], id = csr[j+13], ie = csr[j+14], if_ = csr[j+15];
    unsigned u0 = h[(size_t)i0 * 32 + sub];
    unsigned u1 = h[(size_t)i1 * 32 + sub];
    unsigned u2 = h[(size_t)i2 * 32 + sub];
    unsigned u3 = h[(size_t)i3 * 32 + sub];
    unsigned u4 = h[(size_t)i4 * 32 + sub];
    unsigned u5 = h[(size_t)i5 * 32 + sub];
    unsigned u6 = h[(size_t)i6 * 32 + sub];
    unsigned u7 = h[(size_t)i7 * 32 + sub];
    unsigned u8 = h[(size_t)i8 * 32 + sub];
    unsigned u9 = h[(size_t)i9 * 32 + sub];
    unsigned ua = h[(size_t)ia * 32 + sub];
    unsigned ub = h[(size_t)ib * 32 + sub];
    unsigned uc = h[(size_t)ic * 32 + sub];
    unsigned ud = h[(size_t)id * 32 + sub];
    unsigned ue = h[(size_t)ie * 32 + sub];
    unsigned uf = h[(size_t)if_ * 32 + sub];
    ACC2(u0) ACC2(u1) ACC2(u2) ACC2(u3) ACC2(u4) ACC2(u5) ACC2(u6) ACC2(u7)
    ACC2(u8) ACC2(u9) ACC2(ua) ACC2(ub) ACC2(uc) ACC2(ud) ACC2(ue) ACC2(uf)
  }
  for (; j + 4 <= hi; j += 4) {
    int i0 = csr[j+0], i1 = csr[j+1], i2 = csr[j+2], i3 = csr[j+3];
    unsigned u0 = h[(size_t)i0 * 32 + sub];
    unsigned u1 = h[(size_t)i1 * 32 + sub];
    unsigned u2 = h[(size_t)i2 * 32 + sub];
    unsigned u3 = h[(size_t)i3 * 32 + sub];
    ACC2(u0) ACC2(u1) ACC2(u2) ACC2(u3)
  }
  for (; j < hi; ++j) {
    int i0 = csr[j];
    unsigned u = h[(size_t)i0 * 32 + sub];
    ACC2(u)
  }
#undef ACC2
  float scn = nd[node];
  float2 bb = ((const float2*)b2)[sub];
  float v0 = s0f * scn + bb.x;
  float v1 = s1f * scn + bb.y;
  float2 o;
  o.x = 1.f / (1.f + expf(-v0));
  o.y = 1.f / (1.f + expf(-v1));
  ((float2*)out)[(size_t)node * 32 + sub] = o;
}

extern "C" void kernel_launch(void* const* d_in, const int* in_sizes, int n_in,
                              void* d_out, int out_size, void* d_ws, size_t ws_size,
                              hipStream_t stream) {
  const float* feat = (const float*)d_in[0];
  const int*   src  = (const int*)d_in[1];
  const int*   dst  = (const int*)d_in[2];
  const float* W1   = (const float*)d_in[3];
  const float* b1   = (const float*)d_in[4];
  const float* W2   = (const float*)d_in[5];
  const float* b2   = (const float*)d_in[6];
  float* out = (float*)d_out;

  const int N = in_sizes[0] / IN_F;   // 100000
  const int E = in_sizes[1];          // 1600000

  const int NBK  = (N + 255) >> 8;            // 391 coarse buckets
  const int NBLK = (E + EPB - 1) / EPB;       // 391 sort blocks
  const int HLEN = 2 * NBK * NBLK;

  size_t off = 0;
  auto alloc = [&](size_t bytes) -> void* {
    void* p = (char*)d_ws + off;
    off = (off + bytes + 255) & ~(size_t)255;
    return p;
  };
  int*    hist    = (int*)alloc((size_t)HLEN * 4);
  int*    P       = (int*)alloc((size_t)(HLEN + 1) * 4);
  int*    bsum    = (int*)alloc((size_t)1024 * 4);
  int2*   pairs_d = (int2*)alloc((size_t)E * 8);
  int*    srcs_s  = (int*)alloc((size_t)E * 4);
  float*  norm_s  = (float*)alloc((size_t)N * 4);
  float*  norm_d  = (float*)alloc((size_t)N * 4);
  int*    row_off = (int*)alloc((size_t)(N + 1) * 4);
  int*    csr     = (int*)alloc((size_t)E * 4);
  ushort* w1t     = (ushort*)alloc((size_t)H_F * IN_F * 2);
  ushort* w2t     = (ushort*)alloc((size_t)N_CLS * H_F * 2);
  ushort* h1      = (ushort*)alloc((size_t)N * H_F * 2);
  ushort* x2bf    = (ushort*)alloc((size_t)N * H_F * 2);
  ushort* h2      = (ushort*)alloc((size_t)N * N_CLS * 2);
  (void)ws_size;

  conv_wT<<<(IN_F * H_F + 255) / 256, 256, 0, stream>>>(W1, w1t, IN_F, H_F);
  conv_wT<<<(H_F * N_CLS + 255) / 256, 256, 0, stream>>>(W2, w2t, H_F, N_CLS);

  // graph build (atomic-free)
  hist_kernel<<<NBLK, 256, 0, stream>>>(src, dst, hist, NBK, NBLK, E);
  const int NBS = (HLEN + SCAN_CHUNK - 1) / SCAN_CHUNK;
  scan_part<<<NBS, 256, 0, stream>>>(hist, bsum, HLEN);
  scan_bsum<<<1, 1024, 0, stream>>>(bsum, NBS);
  scan_final<<<NBS, 256, 0, stream>>>(hist, bsum, P, HLEN, 2 * E);
  scatter_kernel<<<NBLK, 256, 0, stream>>>(src, dst, P, pairs_d, srcs_s, NBK, NBLK, E);
  csr_bucket<<<NBK, 256, 0, stream>>>(pairs_d, P, row_off, norm_d, csr, NBK, NBLK, N, E);
  outdeg_bucket<<<NBK, 256, 0, stream>>>(srcs_s, P, norm_s, NBK, NBLK, N, E);

  // layer 1 (conv fused into GEMM A-stage)
  mfma_gemm1<<<(N + 127) / 128, 256, 0, stream>>>(feat, w1t, norm_s, h1, N);
  gather1<<<(N * 64 + 255) / 256, 256, 0, stream>>>(h1, row_off, csr, norm_d, b1, x2bf, N);

  // layer 2
  mfma_gemm_scale<128, 64, 128, 2, 2><<<(N + 127) / 128, 256, 0, stream>>>(
      x2bf, w2t, norm_s, h2, N);
  int pairs = (N + 1) / 2;
  gather2<<<(pairs * 64 + 255) / 256, 256, 0, stream>>>(h2, row_off, csr, norm_d, b2, out, N);
}